// Round 4
// baseline (6999.713 us; speedup 1.0000x reference)
//
#include <hip/hip_runtime.h>
#include <hip/hip_bf16.h>
#include <math.h>

// Problem constants
// B=32 S=256 E=300 H=256(4H=1024) L=4000 D=256 G=512 V=50000 LIN1=512 LIN2=256, 2H=512

// ---------------------------------------------------------------------------
// Generic tiled fp32 GEMM: C[M,N] = A[M,K] * B + epilogue
//   BT=true : B is [N][K] row-major ; BT=false: B is [K][N] row-major
//   GATHER  : A row m comes from A + tok[m]*lda  (embedding gather)
// Tile: BM=64, BN=128, BK=16, 256 threads, each thread 4(m)x8(n)
// ---------------------------------------------------------------------------
template<bool BT, bool GATHER>
__global__ __launch_bounds__(256) void gemm_k(
    const float* __restrict__ A, const float* __restrict__ Bm, float* __restrict__ C,
    int M, int N, int K, int lda, int ldb, int ldc,
    long abs_, long bbs_, long cbs_,
    const int* __restrict__ tok,
    const float* __restrict__ bias,
    const float* __restrict__ addrow, int addmod, int ldadd,
    int do_relu)
{
    const int tid = threadIdx.x;
    const int tx = tid & 15;
    const int ty = tid >> 4;
    const int n0 = blockIdx.x * 128;
    const int m0 = blockIdx.y * 64;
    const int z  = blockIdx.z;
    A  += (size_t)z * abs_;
    Bm += (size_t)z * bbs_;
    C  += (size_t)z * cbs_;

    __shared__ float As[16][68];
    __shared__ float Bs[16][132];

    float acc[4][8];
#pragma unroll
    for (int i = 0; i < 4; ++i)
#pragma unroll
        for (int j = 0; j < 8; ++j) acc[i][j] = 0.f;

    const int ksteps = (K + 15) / 16;
    for (int kt = 0; kt < ksteps; ++kt) {
        const int k0 = kt * 16;
#pragma unroll
        for (int j = 0; j < 4; ++j) {
            int e  = tid + j * 256;
            int kk = e & 15;
            int m  = e >> 4;
            int gm = m0 + m, gk = k0 + kk;
            float v = 0.f;
            if (gm < M && gk < K) {
                size_t rb;
                if (GATHER) rb = (size_t)tok[gm] * lda;
                else        rb = (size_t)gm * lda;
                v = A[rb + gk];
            }
            As[kk][m] = v;
        }
#pragma unroll
        for (int j = 0; j < 8; ++j) {
            int e = tid + j * 256;
            if (BT) {
                int kk = e & 15;
                int n  = e >> 4;
                int gn = n0 + n, gk = k0 + kk;
                Bs[kk][n] = (gn < N && gk < K) ? Bm[(size_t)gn * ldb + gk] : 0.f;
            } else {
                int n  = e & 127;
                int kk = e >> 7;
                int gn = n0 + n, gk = k0 + kk;
                Bs[kk][n] = (gn < N && gk < K) ? Bm[(size_t)gk * ldb + gn] : 0.f;
            }
        }
        __syncthreads();
#pragma unroll
        for (int kk = 0; kk < 16; ++kk) {
            const float4 av  = *(const float4*)&As[kk][ty * 4];
            const float4 b0v = *(const float4*)&Bs[kk][tx * 8];
            const float4 b1v = *(const float4*)&Bs[kk][tx * 8 + 4];
            const float a_[4] = {av.x, av.y, av.z, av.w};
            const float b_[8] = {b0v.x, b0v.y, b0v.z, b0v.w, b1v.x, b1v.y, b1v.z, b1v.w};
#pragma unroll
            for (int i = 0; i < 4; ++i)
#pragma unroll
                for (int j = 0; j < 8; ++j) acc[i][j] = fmaf(a_[i], b_[j], acc[i][j]);
        }
        __syncthreads();
    }

#pragma unroll
    for (int i = 0; i < 4; ++i) {
        const int gm = m0 + ty * 4 + i;
        if (gm >= M) continue;
        const float* addp = addrow ? (addrow + (size_t)(gm % addmod) * ldadd) : nullptr;
#pragma unroll
        for (int j = 0; j < 8; ++j) {
            const int gn = n0 + tx * 8 + j;
            if (gn >= N) continue;
            float v = acc[i][j];
            if (bias) v += bias[gn];
            if (addp) v += addp[gn];
            if (do_relu) v = fmaxf(v, 0.f);
            C[(size_t)gm * ldc + gn] = v;
        }
    }
}

// ---------------------------------------------------------------------------
// 128x128 tile fp32 GEMM, 256 threads, 8x8 micro-tile (2x FLOP/LDS-read of gemm_k)
// ---------------------------------------------------------------------------
template<bool BT, bool GATHER>
__global__ __launch_bounds__(256) void gemm2_k(
    const float* __restrict__ A, const float* __restrict__ Bm, float* __restrict__ C,
    int M, int N, int K, int lda, int ldb, int ldc,
    long abs_, long bbs_, long cbs_,
    const int* __restrict__ tok,
    const float* __restrict__ bias,
    const float* __restrict__ addrow, int addmod, int ldadd,
    int do_relu)
{
    const int tid = threadIdx.x;
    const int tx = tid & 15;        // n: 16 threads x 8
    const int ty = tid >> 4;        // m: 16 threads x 8
    const int n0 = blockIdx.x * 128;
    const int m0 = blockIdx.y * 128;
    const int z  = blockIdx.z;
    A  += (size_t)z * abs_;
    Bm += (size_t)z * bbs_;
    C  += (size_t)z * cbs_;

    __shared__ float As[16][132];
    __shared__ float Bs[16][132];

    float acc[8][8];
#pragma unroll
    for (int i = 0; i < 8; ++i)
#pragma unroll
        for (int j = 0; j < 8; ++j) acc[i][j] = 0.f;

    const int ksteps = (K + 15) / 16;
    for (int kt = 0; kt < ksteps; ++kt) {
        const int k0 = kt * 16;
        // A stage: 128m x 16k, 8 elems/thread
#pragma unroll
        for (int j = 0; j < 8; ++j) {
            int e  = tid + j * 256;
            int kk = e & 15;
            int m  = e >> 4;
            int gm = m0 + m, gk = k0 + kk;
            float v = 0.f;
            if (gm < M && gk < K) {
                size_t rb;
                if (GATHER) rb = (size_t)tok[gm] * lda;
                else        rb = (size_t)gm * lda;
                v = A[rb + gk];
            }
            As[kk][m] = v;
        }
        // B stage: 16k x 128n, 8 elems/thread
#pragma unroll
        for (int j = 0; j < 8; ++j) {
            int e = tid + j * 256;
            if (BT) {
                int kk = e & 15;
                int n  = e >> 4;
                int gn = n0 + n, gk = k0 + kk;
                Bs[kk][n] = (gn < N && gk < K) ? Bm[(size_t)gn * ldb + gk] : 0.f;
            } else {
                int n  = e & 127;
                int kk = e >> 7;
                int gn = n0 + n, gk = k0 + kk;
                Bs[kk][n] = (gn < N && gk < K) ? Bm[(size_t)gk * ldb + gn] : 0.f;
            }
        }
        __syncthreads();
#pragma unroll
        for (int kk = 0; kk < 16; ++kk) {
            const float4 a0v = *(const float4*)&As[kk][ty * 8];
            const float4 a1v = *(const float4*)&As[kk][ty * 8 + 4];
            const float4 b0v = *(const float4*)&Bs[kk][tx * 8];
            const float4 b1v = *(const float4*)&Bs[kk][tx * 8 + 4];
            const float a_[8] = {a0v.x, a0v.y, a0v.z, a0v.w, a1v.x, a1v.y, a1v.z, a1v.w};
            const float b_[8] = {b0v.x, b0v.y, b0v.z, b0v.w, b1v.x, b1v.y, b1v.z, b1v.w};
#pragma unroll
            for (int i = 0; i < 8; ++i)
#pragma unroll
                for (int j = 0; j < 8; ++j) acc[i][j] = fmaf(a_[i], b_[j], acc[i][j]);
        }
        __syncthreads();
    }

#pragma unroll
    for (int i = 0; i < 8; ++i) {
        const int gm = m0 + ty * 8 + i;
        if (gm >= M) continue;
        const float* addp = addrow ? (addrow + (size_t)(gm % addmod) * ldadd) : nullptr;
#pragma unroll
        for (int j = 0; j < 8; ++j) {
            const int gn = n0 + tx * 8 + j;
            if (gn >= N) continue;
            float v = acc[i][j];
            if (bias) v += bias[gn];
            if (addp) v += addp[gn];
            if (do_relu) v = fmaxf(v, 0.f);
            C[(size_t)gm * ldc + gn] = v;
        }
    }
}

// ---------------------------------------------------------------------------
// Register-resident biLSTM scan, low-latency stamp protocol.
// grid = (64 pairs, 4 quarters), 1024 threads. Per step serial chain:
//   h-store -> release stamp store -> partner 4x relaxed poll -> acquire fence -> h-load
// 3 barriers/step; fast __expf activations; xg prefetched 1 step ahead.
// Co-residency: 256 blocks <= 256 CUs (1 block/CU) => no deadlock.
// ---------------------------------------------------------------------------
__global__ __launch_bounds__(1024) void lstm_reg_k(
    const float* __restrict__ gxf, const float* __restrict__ gxb,
    const float* __restrict__ whf, const float* __restrict__ whb,
    float* __restrict__ rnn, float* hbuf, int* stamp)
{
    const int p = blockIdx.x;          // pair: batch b=p>>1, dir=p&1
    const int q = blockIdx.y;          // quarter (owns units [64q,64q+64))
    const int b = p >> 1, dir = p & 1;
    const float* xg = dir ? gxb : gxf;
    const float* W  = dir ? whb : whf;
    const int tid = threadIdx.x;
    const int row = tid >> 2;          // block-local gate row 0..255
    const int ks  = tid & 3;           // 64-float k-slice
    const int grow = (row >> 6) * 256 + q * 64 + (row & 63);

    // W row slice -> 16 float4 (64 regs), loaded once
    float4 w[16];
    {
        const float4* wp = (const float4*)(W + (size_t)grow * 256 + ks * 64);
#pragma unroll
        for (int i = 0; i < 16; ++i) w[i] = wp[i];
    }

    __shared__ float h_lds[4 * 68];
    __shared__ float xg_lds[256];
    __shared__ float g_lds[256];

    float* hb0 = hbuf + (size_t)p * 256;            // parity 0
    float* hb1 = hbuf + (size_t)(64 + p) * 256;     // parity 1
    int* sp = stamp + p * 16;                       // stamps of the 4 partners

    const size_t xgb = (size_t)b * 256;
    const int g2 = (tid >> 6) * 256 + q * 64 + (tid & 63);  // valid for tid<256
    float c = 0.f;
    float xg_cur = 0.f;
    if (tid < 256) xg_cur = xg[(xgb + (dir ? 255 : 0)) * 1024 + g2];

    for (int st = 0; st < 256; ++st) {
        const int ts = dir ? 255 - st : st;
        if (st > 0 && tid == 0) {
            while (true) {
                int s0 = __hip_atomic_load(&sp[0], __ATOMIC_RELAXED, __HIP_MEMORY_SCOPE_AGENT);
                int s1 = __hip_atomic_load(&sp[1], __ATOMIC_RELAXED, __HIP_MEMORY_SCOPE_AGENT);
                int s2 = __hip_atomic_load(&sp[2], __ATOMIC_RELAXED, __HIP_MEMORY_SCOPE_AGENT);
                int s3 = __hip_atomic_load(&sp[3], __ATOMIC_RELAXED, __HIP_MEMORY_SCOPE_AGENT);
                if (min(min(s0, s1), min(s2, s3)) >= st) break;
            }
            __builtin_amdgcn_fence(__ATOMIC_ACQUIRE, "agent");
        }
        __syncthreads();   // B1: partners' h[st-1] published; prev act done
        if (tid < 256) {
            float hv = 0.f;
            if (st > 0) {
                const float* src = (st & 1) ? hb0 : hb1;   // parity (st-1)&1
                hv = __hip_atomic_load(&src[tid], __ATOMIC_RELAXED, __HIP_MEMORY_SCOPE_AGENT);
            }
            h_lds[(tid >> 6) * 68 + (tid & 63)] = hv;
            xg_lds[tid] = xg_cur;
        }
        __syncthreads();   // B2: h_lds/xg_lds ready
        float acc = 0.f;
        {
            const float4* hp = (const float4*)&h_lds[ks * 68];
#pragma unroll
            for (int i = 0; i < 16; ++i) {
                const float4 hv = hp[i];
                acc = fmaf(w[i].x, hv.x, acc);
                acc = fmaf(w[i].y, hv.y, acc);
                acc = fmaf(w[i].z, hv.z, acc);
                acc = fmaf(w[i].w, hv.w, acc);
            }
        }
        acc += __shfl_xor(acc, 1);
        acc += __shfl_xor(acc, 2);
        if (ks == 0) g_lds[row] = acc;
        __syncthreads();   // B3: gate dots ready
        if (tid < 64) {    // wave 0 only: act + publish (wave-local release)
            const float gi = g_lds[tid]       + xg_lds[tid];
            const float gf = g_lds[64 + tid]  + xg_lds[64 + tid];
            const float gg = g_lds[128 + tid] + xg_lds[128 + tid];
            const float go = g_lds[192 + tid] + xg_lds[192 + tid];
            const float si = 1.f / (1.f + __expf(-gi));
            const float sf = 1.f / (1.f + __expf(-gf));
            const float so = 1.f / (1.f + __expf(-go));
            const float tg = 1.f - 2.f / (__expf(2.f * gg) + 1.f);
            c = sf * c + si * tg;
            const float tc = 1.f - 2.f / (__expf(2.f * c) + 1.f);
            const float hn = so * tc;
            float* dst = (st & 1) ? hb1 : hb0;              // parity st&1
            __hip_atomic_store(&dst[q * 64 + tid], hn, __ATOMIC_RELAXED, __HIP_MEMORY_SCOPE_AGENT);
            if (tid == 0) {  // release: drains this wave's 64 h-stores first
                __hip_atomic_store(&sp[q], st + 1, __ATOMIC_RELEASE, __HIP_MEMORY_SCOPE_AGENT);
            }
            rnn[(xgb + ts) * 512 + (size_t)dir * 256 + q * 64 + tid] = hn;
        }
        // prefetch next step's xg (off critical path; consumed after next B1)
        if (tid < 256 && st < 255) {
            const int tsn = dir ? 254 - st : st + 1;
            xg_cur = xg[(xgb + tsn) * 1024 + g2];
        }
    }
}

__global__ void init_cnt_k(int* stamp) {
    const int i = blockIdx.x * blockDim.x + threadIdx.x;
    if (i < 1024) stamp[i] = 0;
}

// ---------------------------------------------------------------------------
// Masked softmax over s (256) per (bb,l) row, in place. grid=(1000, nb), 256 thr.
// ---------------------------------------------------------------------------
__global__ __launch_bounds__(256) void softmax_k(
    float* __restrict__ sc, const int* __restrict__ tokens, int b0)
{
    const int bb = blockIdx.y;
    const int l  = blockIdx.x * 4 + (threadIdx.x >> 6);
    const int lane = threadIdx.x & 63;
    float* row = sc + ((size_t)bb * 4000 + l) * 256;
    const int* tk = tokens + (size_t)(b0 + bb) * 256;
    float4 v = *(const float4*)&row[lane * 4];
    const int4 tv = *(const int4*)&tk[lane * 4];
    if (tv.x == 0) v.x = -1e9f;
    if (tv.y == 0) v.y = -1e9f;
    if (tv.z == 0) v.z = -1e9f;
    if (tv.w == 0) v.w = -1e9f;
    float mx = fmaxf(fmaxf(v.x, v.y), fmaxf(v.z, v.w));
    for (int o = 32; o > 0; o >>= 1) mx = fmaxf(mx, __shfl_xor(mx, o));
    v.x = __expf(v.x - mx); v.y = __expf(v.y - mx);
    v.z = __expf(v.z - mx); v.w = __expf(v.w - mx);
    float s = v.x + v.y + v.z + v.w;
    for (int o = 32; o > 0; o >>= 1) s += __shfl_xor(s, o);
    const float inv = 1.f / s;
    v.x *= inv; v.y *= inv; v.z *= inv; v.w *= inv;
    *(float4*)&row[lane * 4] = v;
}

// ---------------------------------------------------------------------------
// Sparse GCN aggregation: out[l,:] = relu(sum_j adj[l,j]*tmp[j,:] + bias).
// ---------------------------------------------------------------------------
__global__ __launch_bounds__(256) void spmm_k(
    const float* __restrict__ adj, const float* __restrict__ tmp,
    const float* __restrict__ bias, float* __restrict__ outp)
{
    const int l = blockIdx.x;
    __shared__ int   idxs[4][256];
    __shared__ float vals[4][256];
    __shared__ int   cnts[4];
    const int t = threadIdx.x;
    const int w = t >> 6, lane = t & 63;
    const float* arow = adj + (size_t)l * 4000;
    int cnt = 0;
    for (int r = 0; r < 16; ++r) {
        const int o = r * 64 + lane;
        const int j = w * 1000 + o;
        const float a = (o < 1000) ? arow[j] : 0.f;
        const unsigned long long mk = __ballot(a != 0.f);
        if (a != 0.f) {
            const int pos = cnt + __popcll(mk & ((1ull << lane) - 1ull));
            if (pos < 256) { idxs[w][pos] = j; vals[w][pos] = a; }
        }
        cnt += __popcll(mk);
    }
    if (lane == 0) cnts[w] = min(cnt, 256);
    __syncthreads();
    const int c0 = t * 2;
    float a0 = 0.f, a1 = 0.f;
    for (int ww = 0; ww < 4; ++ww) {
        const int n = cnts[ww];
        for (int e = 0; e < n; ++e) {
            const float a = vals[ww][e];
            const float2 tv = *(const float2*)&tmp[(size_t)idxs[ww][e] * 512 + c0];
            a0 = fmaf(a, tv.x, a0);
            a1 = fmaf(a, tv.y, a1);
        }
    }
    float2 res;
    res.x = fmaxf(a0 + bias[c0], 0.f);
    res.y = fmaxf(a1 + bias[c0 + 1], 0.f);
    *(float2*)&outp[(size_t)l * 512 + c0] = res;
}

// ---------------------------------------------------------------------------
// Final projection: out[b0+bb, l] = dot(x2[r,:256], w_out) + b_out.
// ---------------------------------------------------------------------------
__global__ __launch_bounds__(256) void out_k(
    const float* __restrict__ x2, const float* __restrict__ w_out,
    const float* __restrict__ b_out, float* __restrict__ outp, int b0)
{
    const int r = blockIdx.x * 4 + (threadIdx.x >> 6);
    const int lane = threadIdx.x & 63;
    const float4 xv = *(const float4*)&x2[(size_t)r * 256 + lane * 4];
    const float4 wv = *(const float4*)&w_out[lane * 4];
    float s = xv.x * wv.x + xv.y * wv.y + xv.z * wv.z + xv.w * wv.w;
    for (int o = 32; o > 0; o >>= 1) s += __shfl_xor(s, o);
    if (lane == 0) {
        const int bb = r / 4000, l = r - bb * 4000;
        outp[(size_t)(b0 + bb) * 4000 + l] = s + b_out[0];
    }
}

// ---------------------------------------------------------------------------
extern "C" void kernel_launch(void* const* d_in, const int* in_sizes, int n_in,
                              void* d_out, int out_size, void* d_ws, size_t ws_size,
                              hipStream_t stream)
{
    const int*   tokens    = (const int*)  d_in[0];
    const float* emb       = (const float*)d_in[1];
    const float* w_ih_f    = (const float*)d_in[2];
    const float* w_hh_f    = (const float*)d_in[3];
    const float* b_f       = (const float*)d_in[4];
    const float* w_ih_b    = (const float*)d_in[5];
    const float* w_hh_b    = (const float*)d_in[6];
    const float* b_b       = (const float*)d_in[7];
    const float* attn_w    = (const float*)d_in[8];
    const float* label_emb = (const float*)d_in[9];
    const float* adj       = (const float*)d_in[10];
    const float* gcn_w     = (const float*)d_in[11];
    const float* gcn_b     = (const float*)d_in[12];
    const float* w1        = (const float*)d_in[13];
    const float* b1        = (const float*)d_in[14];
    const float* w2        = (const float*)d_in[15];
    const float* b2        = (const float*)d_in[16];
    const float* w_out     = (const float*)d_in[17];
    const float* b_out     = (const float*)d_in[18];
    float* outp = (float*)d_out;
    float* wsf  = (float*)d_ws;

    // workspace layout (floats)
    const size_t off_gf  = 0;          // gates_f  8192*1024
    const size_t off_gb  = 8388608;    // gates_b  8192*1024
    const size_t off_rnn = 16777216;   // rnn      8192*512
    const size_t off_tmp = 20971520;   // gcn_tmp  4000*512  (lstm hbuf/stamp overlay)
    const size_t off_go  = 23019520;   // gcn_out  4000*512
    const size_t off_ctr = 25067520;   // contrib  4000*512
    const size_t base_end = 27115520;
    const size_t have = ws_size / 4;
    int NB; size_t off_chunk;
    if      (have >= base_end + 4ul * 6144000) { NB = 4; off_chunk = base_end; }
    else if (have >= base_end + 2ul * 6144000) { NB = 2; off_chunk = base_end; }
    else { NB = 2; off_chunk = off_gf; } // overlay dead gates buffers

    float* gates_f = wsf + off_gf;
    float* gates_b = wsf + off_gb;
    float* rnn     = wsf + off_rnn;
    float* gcn_tmp = wsf + off_tmp;
    float* gcn_out = wsf + off_go;
    float* contrib = wsf + off_ctr;
    float* hbuf    = wsf + off_tmp;                  // [2][64][256]
    int*   stamp   = (int*)(wsf + off_tmp + 32768);  // [64][16]
    float* scoresb = wsf + off_chunk;
    float* attnb   = scoresb + (size_t)NB * 1024000;
    float* x1b     = attnb   + (size_t)NB * 2048000;
    float* x2b     = x1b     + (size_t)NB * 2048000;

    // 0. zero lstm stamps (graph-replay safe)
    init_cnt_k<<<4, 256, 0, stream>>>(stamp);

    // 1. input projections (embedding gather fused): gates = emb[tok] @ w_ih^T + b
    gemm2_k<true, true><<<dim3(8, 64, 1), 256, 0, stream>>>(
        emb, w_ih_f, gates_f, 8192, 1024, 300, 300, 300, 1024,
        0, 0, 0, tokens, b_f, nullptr, 1, 0, 0);
    gemm2_k<true, true><<<dim3(8, 64, 1), 256, 0, stream>>>(
        emb, w_ih_b, gates_b, 8192, 1024, 300, 300, 300, 1024,
        0, 0, 0, tokens, b_b, nullptr, 1, 0, 0);

    // 2. biLSTM scan -> rnn [B,S,512]
    lstm_reg_k<<<dim3(64, 4), 1024, 0, stream>>>(
        gates_f, gates_b, w_hh_f, w_hh_b, rnn, hbuf, stamp);

    // 3. GCN branch (batch independent)
    gemm_k<false, false><<<dim3(4, 63, 1), 256, 0, stream>>>(
        label_emb, gcn_w, gcn_tmp, 4000, 512, 256, 256, 512, 512,
        0, 0, 0, nullptr, nullptr, nullptr, 1, 0, 0);
    spmm_k<<<dim3(4000), 256, 0, stream>>>(adj, gcn_tmp, gcn_b, gcn_out);
    gemm_k<false, false><<<dim3(4, 63, 1), 256, 0, stream>>>(
        gcn_out, w1 + (size_t)512 * 512, contrib, 4000, 512, 512, 512, 512, 512,
        0, 0, 0, nullptr, b1, nullptr, 1, 0, 0);

    // 4. attention + MLP head, chunked over batch
    for (int b0 = 0; b0 < 32; b0 += NB) {
        const int nb = (32 - b0 < NB) ? (32 - b0) : NB;
        gemm2_k<true, false><<<dim3(2, 32, nb), 256, 0, stream>>>(
            attn_w, rnn + (size_t)b0 * 131072, scoresb, 4000, 256, 512, 512, 512, 256,
            0, 131072, 1024000, nullptr, nullptr, nullptr, 1, 0, 0);
        softmax_k<<<dim3(1000, nb), 256, 0, stream>>>(scoresb, tokens, b0);
        gemm2_k<false, false><<<dim3(4, 32, nb), 256, 0, stream>>>(
            scoresb, rnn + (size_t)b0 * 131072, attnb, 4000, 512, 256, 256, 512, 512,
            1024000, 131072, 2048000, nullptr, nullptr, nullptr, 1, 0, 0);
        gemm2_k<false, false><<<dim3(4, (nb * 4000 + 127) / 128, 1), 256, 0, stream>>>(
            attnb, w1, x1b, nb * 4000, 512, 512, 512, 512, 512,
            0, 0, 0, nullptr, nullptr, contrib, 4000, 512, 1);
        gemm2_k<false, false><<<dim3(2, (nb * 4000 + 127) / 128, 1), 256, 0, stream>>>(
            x1b, w2, x2b, nb * 4000, 256, 512, 512, 256, 256,
            0, 0, 0, nullptr, b2, nullptr, 1, 0, 1);
        out_k<<<dim3(nb * 1000), 256, 0, stream>>>(x2b, w_out, b_out, outp, b0);
    }
}

// Round 5
// 2878.795 us; speedup vs baseline: 2.4315x; 2.4315x over previous
//
#include <hip/hip_runtime.h>
#include <hip/hip_bf16.h>
#include <math.h>

// Problem constants
// B=32 S=256 E=300 H=256(4H=1024) L=4000 D=256 G=512 V=50000 LIN1=512 LIN2=256, 2H=512

typedef __attribute__((ext_vector_type(8))) short bfrag;   // 8 bf16 (4 VGPRs)
typedef __attribute__((ext_vector_type(4))) float ffrag;   // 4 fp32 acc

__device__ __forceinline__ ushort f2bf(float x) {
    union { float f; unsigned u; } c; c.f = x;
    const unsigned r = c.u + 0x7fffu + ((c.u >> 16) & 1u);
    return (ushort)(r >> 16);
}
__device__ __forceinline__ float bf2f(ushort h) {
    union { unsigned u; float f; } c; c.u = (unsigned)h << 16;
    return c.f;
}

// ---------------------------------------------------------------------------
// fp32 tiled GEMM (64x128 tile) for input-proj (gather) + GCN small gemms.
// ---------------------------------------------------------------------------
template<bool BT, bool GATHER>
__global__ __launch_bounds__(256) void gemm_k(
    const float* __restrict__ A, const float* __restrict__ Bm, float* __restrict__ C,
    int M, int N, int K, int lda, int ldb, int ldc,
    long abs_, long bbs_, long cbs_,
    const int* __restrict__ tok,
    const float* __restrict__ bias,
    const float* __restrict__ addrow, int addmod, int ldadd,
    int do_relu)
{
    const int tid = threadIdx.x;
    const int tx = tid & 15;
    const int ty = tid >> 4;
    const int n0 = blockIdx.x * 128;
    const int m0 = blockIdx.y * 64;
    const int z  = blockIdx.z;
    A  += (size_t)z * abs_;
    Bm += (size_t)z * bbs_;
    C  += (size_t)z * cbs_;

    __shared__ float As[16][68];
    __shared__ float Bs[16][132];

    float acc[4][8];
#pragma unroll
    for (int i = 0; i < 4; ++i)
#pragma unroll
        for (int j = 0; j < 8; ++j) acc[i][j] = 0.f;

    const int ksteps = (K + 15) / 16;
    for (int kt = 0; kt < ksteps; ++kt) {
        const int k0 = kt * 16;
#pragma unroll
        for (int j = 0; j < 4; ++j) {
            int e  = tid + j * 256;
            int kk = e & 15;
            int m  = e >> 4;
            int gm = m0 + m, gk = k0 + kk;
            float v = 0.f;
            if (gm < M && gk < K) {
                size_t rb;
                if (GATHER) rb = (size_t)tok[gm] * lda;
                else        rb = (size_t)gm * lda;
                v = A[rb + gk];
            }
            As[kk][m] = v;
        }
#pragma unroll
        for (int j = 0; j < 8; ++j) {
            int e = tid + j * 256;
            if (BT) {
                int kk = e & 15;
                int n  = e >> 4;
                int gn = n0 + n, gk = k0 + kk;
                Bs[kk][n] = (gn < N && gk < K) ? Bm[(size_t)gn * ldb + gk] : 0.f;
            } else {
                int n  = e & 127;
                int kk = e >> 7;
                int gn = n0 + n, gk = k0 + kk;
                Bs[kk][n] = (gn < N && gk < K) ? Bm[(size_t)gk * ldb + gn] : 0.f;
            }
        }
        __syncthreads();
#pragma unroll
        for (int kk = 0; kk < 16; ++kk) {
            const float4 av  = *(const float4*)&As[kk][ty * 4];
            const float4 b0v = *(const float4*)&Bs[kk][tx * 8];
            const float4 b1v = *(const float4*)&Bs[kk][tx * 8 + 4];
            const float a_[4] = {av.x, av.y, av.z, av.w};
            const float b_[8] = {b0v.x, b0v.y, b0v.z, b0v.w, b1v.x, b1v.y, b1v.z, b1v.w};
#pragma unroll
            for (int i = 0; i < 4; ++i)
#pragma unroll
                for (int j = 0; j < 8; ++j) acc[i][j] = fmaf(a_[i], b_[j], acc[i][j]);
        }
        __syncthreads();
    }

#pragma unroll
    for (int i = 0; i < 4; ++i) {
        const int gm = m0 + ty * 4 + i;
        if (gm >= M) continue;
        const float* addp = addrow ? (addrow + (size_t)(gm % addmod) * ldadd) : nullptr;
#pragma unroll
        for (int j = 0; j < 8; ++j) {
            const int gn = n0 + tx * 8 + j;
            if (gn >= N) continue;
            float v = acc[i][j];
            if (bias) v += bias[gn];
            if (addp) v += addp[gn];
            if (do_relu) v = fmaxf(v, 0.f);
            C[(size_t)gm * ldc + gn] = v;
        }
    }
}

// ---------------------------------------------------------------------------
// Split-bf16 MFMA GEMM: C = A * B^T in fp32-ish precision via 3-term split.
// A: [M][lda] bf16, row r = [hi(a[r][0..K)) | lo(...)] (lda >= 2K)
// B: [N][ldb] bf16, same split layout (k-contiguous per output column)
// Tile 128x128, BK=32, 256 threads = 4 waves (2x2 of 64x64), per wave 4x4
// frags of 16x16x32 MFMA, 3 MFMAs per frag per k-chunk (hh + hl + lh).
// LDS rows padded to 40 bf16 (80B stride) -> conflict-free b128 frag reads.
// Epilogue: optional bias / addrow / relu; out fp32 and/or split-bf16.
// ---------------------------------------------------------------------------
template<bool BIAS, bool ADDROW, bool RELU, bool OUTF, bool OUTS>
__global__ __launch_bounds__(256) void mgemm_k(
    const ushort* __restrict__ A, const ushort* __restrict__ B,
    float* __restrict__ Cf, ushort* __restrict__ Cs,
    int M, int N, int K, int lda, int ldb, int ldc, int ldcs,
    long abs_, long bbs_, long cbs_, long csbs_,
    const float* __restrict__ bias,
    const float* __restrict__ addrow, int addmod, int ldadd)
{
    const int tid = threadIdx.x;
    const int ln = tid & 63;
    const int wv = tid >> 6;
    const int wm = wv >> 1, wn = wv & 1;
    const int m0 = blockIdx.x * 128, n0 = blockIdx.y * 128;
    const int z = blockIdx.z;
    A += (size_t)z * abs_;
    B += (size_t)z * bbs_;

    __shared__ ushort Ah[128 * 40], Al[128 * 40], Bh[128 * 40], Bl[128 * 40];

    ffrag acc[4][4];
#pragma unroll
    for (int i = 0; i < 4; ++i)
#pragma unroll
        for (int j = 0; j < 4; ++j) acc[i][j] = ffrag{0.f, 0.f, 0.f, 0.f};

    const int sr = tid >> 1;             // staging row 0..127
    const int sk = (tid & 1) * 16;       // staging k offset (0/16)
    const int am = min(m0 + sr, M - 1);  // clamped A row (writes masked later)
    const int bn = n0 + sr;              // B row (N % 128 == 0 always)
    const int fr = ln & 15;              // fragment row/col
    const int fk = (ln >> 4) * 8;        // fragment k offset

    const ushort* arow = A + (size_t)am * lda;
    const ushort* brow = B + (size_t)bn * ldb;

    for (int k0 = 0; k0 < K; k0 += 32) {
        const ushort* ap = arow + k0 + sk;
        const ushort* bp = brow + k0 + sk;
        const bfrag ah0 = *(const bfrag*)ap;
        const bfrag ah1 = *(const bfrag*)(ap + 8);
        const bfrag al0 = *(const bfrag*)(ap + K);
        const bfrag al1 = *(const bfrag*)(ap + K + 8);
        const bfrag bh0 = *(const bfrag*)bp;
        const bfrag bh1 = *(const bfrag*)(bp + 8);
        const bfrag bl0 = *(const bfrag*)(bp + K);
        const bfrag bl1 = *(const bfrag*)(bp + K + 8);
        __syncthreads();   // previous iteration's frag reads complete
        *(bfrag*)&Ah[sr * 40 + sk] = ah0;  *(bfrag*)&Ah[sr * 40 + sk + 8] = ah1;
        *(bfrag*)&Al[sr * 40 + sk] = al0;  *(bfrag*)&Al[sr * 40 + sk + 8] = al1;
        *(bfrag*)&Bh[sr * 40 + sk] = bh0;  *(bfrag*)&Bh[sr * 40 + sk + 8] = bh1;
        *(bfrag*)&Bl[sr * 40 + sk] = bl0;  *(bfrag*)&Bl[sr * 40 + sk + 8] = bl1;
        __syncthreads();   // tile staged
        bfrag afh[4], afl[4], bfh[4], bfl[4];
#pragma unroll
        for (int i = 0; i < 4; ++i) {
            const int ar = (wm * 64 + i * 16 + fr) * 40 + fk;
            const int br = (wn * 64 + i * 16 + fr) * 40 + fk;
            afh[i] = *(const bfrag*)&Ah[ar];
            afl[i] = *(const bfrag*)&Al[ar];
            bfh[i] = *(const bfrag*)&Bh[br];
            bfl[i] = *(const bfrag*)&Bl[br];
        }
#pragma unroll
        for (int i = 0; i < 4; ++i)
#pragma unroll
            for (int j = 0; j < 4; ++j) {
                acc[i][j] = __builtin_amdgcn_mfma_f32_16x16x32_bf16(afh[i], bfh[j], acc[i][j], 0, 0, 0);
                acc[i][j] = __builtin_amdgcn_mfma_f32_16x16x32_bf16(afh[i], bfl[j], acc[i][j], 0, 0, 0);
                acc[i][j] = __builtin_amdgcn_mfma_f32_16x16x32_bf16(afl[i], bfh[j], acc[i][j], 0, 0, 0);
            }
    }

    // epilogue: C/D layout col=lane&15, row=(lane>>4)*4+reg  [m89-verified]
#pragma unroll
    for (int i = 0; i < 4; ++i) {
#pragma unroll
        for (int rg = 0; rg < 4; ++rg) {
            const int gm = m0 + wm * 64 + i * 16 + (ln >> 4) * 4 + rg;
            if (gm >= M) continue;
            const float* addp = ADDROW ? (addrow + (size_t)(gm % addmod) * ldadd) : nullptr;
#pragma unroll
            for (int j = 0; j < 4; ++j) {
                const int gn = n0 + wn * 64 + j * 16 + fr;
                float v = acc[i][j][rg];
                if (BIAS) v += bias[gn];
                if (ADDROW) v += addp[gn];
                if (RELU) v = fmaxf(v, 0.f);
                if (OUTF) Cf[(size_t)z * cbs_ + (size_t)gm * ldc + gn] = v;
                if (OUTS) {
                    const ushort h = f2bf(v);
                    const ushort l = f2bf(v - bf2f(h));
                    ushort* cp = Cs + (size_t)z * csbs_ + (size_t)gm * ldcs;
                    cp[gn] = h;
                    cp[N + gn] = l;
                }
            }
        }
    }
}

// ---------------------------------------------------------------------------
// fp32 [rows][K] -> split bf16 [rows][2K] (hi | lo), same row order
// ---------------------------------------------------------------------------
__global__ void split_k(const float* __restrict__ in, ushort* __restrict__ outp,
                        int rows, int K)
{
    const int i = blockIdx.x * 256 + threadIdx.x;
    if (i >= rows * K) return;
    const int r = i / K, k = i - r * K;
    const float x = in[i];
    const ushort h = f2bf(x);
    const ushort l = f2bf(x - bf2f(h));
    ushort* o = outp + (size_t)r * 2 * K;
    o[k] = h;
    o[K + k] = l;
}

// ---------------------------------------------------------------------------
// fp32 [R][C] (ld ldin) -> split-transposed bf16 [C][2R]: out[c] = [hi(in[:,c]) | lo]
// 64x64 LDS tile, 256 threads. R,C multiples of 64.
// ---------------------------------------------------------------------------
__global__ __launch_bounds__(256) void tsplit_k(
    const float* __restrict__ in, ushort* __restrict__ outp,
    int R, int C, int ldin, long ibs, long obs)
{
    __shared__ float t[64][65];
    const int c0 = blockIdx.x * 64, r0 = blockIdx.y * 64;
    in   += (size_t)blockIdx.z * ibs;
    outp += (size_t)blockIdx.z * obs;
    const int tx = threadIdx.x & 15, ty = threadIdx.x >> 4;
#pragma unroll
    for (int i = 0; i < 4; ++i) {
        const int r = ty * 4 + i;
        const float4 v = *(const float4*)&in[(size_t)(r0 + r) * ldin + c0 + tx * 4];
        t[tx * 4 + 0][r] = v.x;
        t[tx * 4 + 1][r] = v.y;
        t[tx * 4 + 2][r] = v.z;
        t[tx * 4 + 3][r] = v.w;
    }
    __syncthreads();
    const int R2 = 2 * R;
#pragma unroll
    for (int i = 0; i < 4; ++i) {
        const int c = ty * 4 + i;
        ushort h[4], l[4];
#pragma unroll
        for (int k2 = 0; k2 < 4; ++k2) {
            const float x = t[c][tx * 4 + k2];
            h[k2] = f2bf(x);
            l[k2] = f2bf(x - bf2f(h[k2]));
        }
        uint2 hw, lw;
        hw.x = (unsigned)h[0] | ((unsigned)h[1] << 16);
        hw.y = (unsigned)h[2] | ((unsigned)h[3] << 16);
        lw.x = (unsigned)l[0] | ((unsigned)l[1] << 16);
        lw.y = (unsigned)l[2] | ((unsigned)l[3] << 16);
        *(uint2*)&outp[(size_t)(c0 + c) * R2 + r0 + tx * 4] = hw;
        *(uint2*)&outp[(size_t)(c0 + c) * R2 + R + r0 + tx * 4] = lw;
    }
}

// ---------------------------------------------------------------------------
// Register-resident biLSTM scan (unchanged from R4; 1255us, latency-bound).
// ---------------------------------------------------------------------------
__global__ __launch_bounds__(1024) void lstm_reg_k(
    const float* __restrict__ gxf, const float* __restrict__ gxb,
    const float* __restrict__ whf, const float* __restrict__ whb,
    float* __restrict__ rnn, float* hbuf, int* stamp)
{
    const int p = blockIdx.x;
    const int q = blockIdx.y;
    const int b = p >> 1, dir = p & 1;
    const float* xg = dir ? gxb : gxf;
    const float* W  = dir ? whb : whf;
    const int tid = threadIdx.x;
    const int row = tid >> 2;
    const int ks  = tid & 3;
    const int grow = (row >> 6) * 256 + q * 64 + (row & 63);

    float4 w[16];
    {
        const float4* wp = (const float4*)(W + (size_t)grow * 256 + ks * 64);
#pragma unroll
        for (int i = 0; i < 16; ++i) w[i] = wp[i];
    }

    __shared__ float h_lds[4 * 68];
    __shared__ float xg_lds[256];
    __shared__ float g_lds[256];

    float* hb0 = hbuf + (size_t)p * 256;
    float* hb1 = hbuf + (size_t)(64 + p) * 256;
    int* sp = stamp + p * 16;

    const size_t xgb = (size_t)b * 256;
    const int g2 = (tid >> 6) * 256 + q * 64 + (tid & 63);
    float c = 0.f;
    float xg_cur = 0.f;
    if (tid < 256) xg_cur = xg[(xgb + (dir ? 255 : 0)) * 1024 + g2];

    for (int st = 0; st < 256; ++st) {
        const int ts = dir ? 255 - st : st;
        if (st > 0 && tid == 0) {
            while (true) {
                int s0 = __hip_atomic_load(&sp[0], __ATOMIC_RELAXED, __HIP_MEMORY_SCOPE_AGENT);
                int s1 = __hip_atomic_load(&sp[1], __ATOMIC_RELAXED, __HIP_MEMORY_SCOPE_AGENT);
                int s2 = __hip_atomic_load(&sp[2], __ATOMIC_RELAXED, __HIP_MEMORY_SCOPE_AGENT);
                int s3 = __hip_atomic_load(&sp[3], __ATOMIC_RELAXED, __HIP_MEMORY_SCOPE_AGENT);
                if (min(min(s0, s1), min(s2, s3)) >= st) break;
            }
            __builtin_amdgcn_fence(__ATOMIC_ACQUIRE, "agent");
        }
        __syncthreads();
        if (tid < 256) {
            float hv = 0.f;
            if (st > 0) {
                const float* src = (st & 1) ? hb0 : hb1;
                hv = __hip_atomic_load(&src[tid], __ATOMIC_RELAXED, __HIP_MEMORY_SCOPE_AGENT);
            }
            h_lds[(tid >> 6) * 68 + (tid & 63)] = hv;
            xg_lds[tid] = xg_cur;
        }
        __syncthreads();
        float acc = 0.f;
        {
            const float4* hp = (const float4*)&h_lds[ks * 68];
#pragma unroll
            for (int i = 0; i < 16; ++i) {
                const float4 hv = hp[i];
                acc = fmaf(w[i].x, hv.x, acc);
                acc = fmaf(w[i].y, hv.y, acc);
                acc = fmaf(w[i].z, hv.z, acc);
                acc = fmaf(w[i].w, hv.w, acc);
            }
        }
        acc += __shfl_xor(acc, 1);
        acc += __shfl_xor(acc, 2);
        if (ks == 0) g_lds[row] = acc;
        __syncthreads();
        if (tid < 64) {
            const float gi = g_lds[tid]       + xg_lds[tid];
            const float gf = g_lds[64 + tid]  + xg_lds[64 + tid];
            const float gg = g_lds[128 + tid] + xg_lds[128 + tid];
            const float go = g_lds[192 + tid] + xg_lds[192 + tid];
            const float si = 1.f / (1.f + __expf(-gi));
            const float sf = 1.f / (1.f + __expf(-gf));
            const float so = 1.f / (1.f + __expf(-go));
            const float tg = 1.f - 2.f / (__expf(2.f * gg) + 1.f);
            c = sf * c + si * tg;
            const float tc = 1.f - 2.f / (__expf(2.f * c) + 1.f);
            const float hn = so * tc;
            float* dst = (st & 1) ? hb1 : hb0;
            __hip_atomic_store(&dst[q * 64 + tid], hn, __ATOMIC_RELAXED, __HIP_MEMORY_SCOPE_AGENT);
            if (tid == 0) {
                __hip_atomic_store(&sp[q], st + 1, __ATOMIC_RELEASE, __HIP_MEMORY_SCOPE_AGENT);
            }
            rnn[(xgb + ts) * 512 + (size_t)dir * 256 + q * 64 + tid] = hn;
        }
        if (tid < 256 && st < 255) {
            const int tsn = dir ? 254 - st : st + 1;
            xg_cur = xg[(xgb + tsn) * 1024 + g2];
        }
    }
}

__global__ void init_cnt_k(int* stamp) {
    const int i = blockIdx.x * blockDim.x + threadIdx.x;
    if (i < 1024) stamp[i] = 0;
}

// ---------------------------------------------------------------------------
// Masked softmax over s (256); reads fp32 row, writes split-bf16 probs IN PLACE
// (row: 256 floats -> 256 hi bf16 | 256 lo bf16 = same 1024 bytes).
// ---------------------------------------------------------------------------
__global__ __launch_bounds__(256) void softmax_split_k(
    float* __restrict__ sc, const int* __restrict__ tokens, int b0)
{
    const int bb = blockIdx.y;
    const int l  = blockIdx.x * 4 + (threadIdx.x >> 6);
    const int lane = threadIdx.x & 63;
    float* row = sc + ((size_t)bb * 4000 + l) * 256;
    const int* tk = tokens + (size_t)(b0 + bb) * 256;
    float4 v = *(const float4*)&row[lane * 4];
    const int4 tv = *(const int4*)&tk[lane * 4];
    if (tv.x == 0) v.x = -1e9f;
    if (tv.y == 0) v.y = -1e9f;
    if (tv.z == 0) v.z = -1e9f;
    if (tv.w == 0) v.w = -1e9f;
    float mx = fmaxf(fmaxf(v.x, v.y), fmaxf(v.z, v.w));
    for (int o = 32; o > 0; o >>= 1) mx = fmaxf(mx, __shfl_xor(mx, o));
    v.x = __expf(v.x - mx); v.y = __expf(v.y - mx);
    v.z = __expf(v.z - mx); v.w = __expf(v.w - mx);
    float s = v.x + v.y + v.z + v.w;
    for (int o = 32; o > 0; o >>= 1) s += __shfl_xor(s, o);
    const float inv = 1.f / s;
    const float p0 = v.x * inv, p1 = v.y * inv, p2 = v.z * inv, p3 = v.w * inv;
    const ushort h0 = f2bf(p0), h1 = f2bf(p1), h2 = f2bf(p2), h3 = f2bf(p3);
    const ushort l0 = f2bf(p0 - bf2f(h0)), l1 = f2bf(p1 - bf2f(h1));
    const ushort l2 = f2bf(p2 - bf2f(h2)), l3 = f2bf(p3 - bf2f(h3));
    ushort* orow = (ushort*)row;
    uint2 hw, lw;
    hw.x = (unsigned)h0 | ((unsigned)h1 << 16);
    hw.y = (unsigned)h2 | ((unsigned)h3 << 16);
    lw.x = (unsigned)l0 | ((unsigned)l1 << 16);
    lw.y = (unsigned)l2 | ((unsigned)l3 << 16);
    *(uint2*)&orow[lane * 4] = hw;          // same wave: all reads precede stores
    *(uint2*)&orow[256 + lane * 4] = lw;
}

// ---------------------------------------------------------------------------
// Sparse GCN aggregation (unchanged).
// ---------------------------------------------------------------------------
__global__ __launch_bounds__(256) void spmm_k(
    const float* __restrict__ adj, const float* __restrict__ tmp,
    const float* __restrict__ bias, float* __restrict__ outp)
{
    const int l = blockIdx.x;
    __shared__ int   idxs[4][256];
    __shared__ float vals[4][256];
    __shared__ int   cnts[4];
    const int t = threadIdx.x;
    const int w = t >> 6, lane = t & 63;
    const float* arow = adj + (size_t)l * 4000;
    int cnt = 0;
    for (int r = 0; r < 16; ++r) {
        const int o = r * 64 + lane;
        const int j = w * 1000 + o;
        const float a = (o < 1000) ? arow[j] : 0.f;
        const unsigned long long mk = __ballot(a != 0.f);
        if (a != 0.f) {
            const int pos = cnt + __popcll(mk & ((1ull << lane) - 1ull));
            if (pos < 256) { idxs[w][pos] = j; vals[w][pos] = a; }
        }
        cnt += __popcll(mk);
    }
    if (lane == 0) cnts[w] = min(cnt, 256);
    __syncthreads();
    const int c0 = t * 2;
    float a0 = 0.f, a1 = 0.f;
    for (int ww = 0; ww < 4; ++ww) {
        const int n = cnts[ww];
        for (int e = 0; e < n; ++e) {
            const float a = vals[ww][e];
            const float2 tv = *(const float2*)&tmp[(size_t)idxs[ww][e] * 512 + c0];
            a0 = fmaf(a, tv.x, a0);
            a1 = fmaf(a, tv.y, a1);
        }
    }
    float2 res;
    res.x = fmaxf(a0 + bias[c0], 0.f);
    res.y = fmaxf(a1 + bias[c0 + 1], 0.f);
    *(float2*)&outp[(size_t)l * 512 + c0] = res;
}

// ---------------------------------------------------------------------------
// Final projection (unchanged).
// ---------------------------------------------------------------------------
__global__ __launch_bounds__(256) void out_k(
    const float* __restrict__ x2, const float* __restrict__ w_out,
    const float* __restrict__ b_out, float* __restrict__ outp, int b0)
{
    const int r = blockIdx.x * 4 + (threadIdx.x >> 6);
    const int lane = threadIdx.x & 63;
    const float4 xv = *(const float4*)&x2[(size_t)r * 256 + lane * 4];
    const float4 wv = *(const float4*)&w_out[lane * 4];
    float s = xv.x * wv.x + xv.y * wv.y + xv.z * wv.z + xv.w * wv.w;
    for (int o = 32; o > 0; o >>= 1) s += __shfl_xor(s, o);
    if (lane == 0) {
        const int bb = r / 4000, l = r - bb * 4000;
        outp[(size_t)(b0 + bb) * 4000 + l] = s + b_out[0];
    }
}

// ---------------------------------------------------------------------------
extern "C" void kernel_launch(void* const* d_in, const int* in_sizes, int n_in,
                              void* d_out, int out_size, void* d_ws, size_t ws_size,
                              hipStream_t stream)
{
    const int*   tokens    = (const int*)  d_in[0];
    const float* emb       = (const float*)d_in[1];
    const float* w_ih_f    = (const float*)d_in[2];
    const float* w_hh_f    = (const float*)d_in[3];
    const float* b_f       = (const float*)d_in[4];
    const float* w_ih_b    = (const float*)d_in[5];
    const float* w_hh_b    = (const float*)d_in[6];
    const float* b_b       = (const float*)d_in[7];
    const float* attn_w    = (const float*)d_in[8];
    const float* label_emb = (const float*)d_in[9];
    const float* adj       = (const float*)d_in[10];
    const float* gcn_w     = (const float*)d_in[11];
    const float* gcn_b     = (const float*)d_in[12];
    const float* w1        = (const float*)d_in[13];
    const float* b1        = (const float*)d_in[14];
    const float* w2        = (const float*)d_in[15];
    const float* b2        = (const float*)d_in[16];
    const float* w_out     = (const float*)d_in[17];
    const float* b_out     = (const float*)d_in[18];
    float* outp = (float*)d_out;
    float* wsf  = (float*)d_ws;

    // ---- workspace layout (float offsets) ----
    const size_t off_gf  = 0;          // gates_f 8.39M (dead after lstm)
    const size_t off_gb  = 8388608;    // gates_b 8.39M (dead after lstm)
    const size_t off_rnn = 16777216;   // rnn fp32 4.19M
    const size_t off_tmp = 20971520;   // gcn_tmp 2.05M (lstm hbuf/stamp overlay)
    const size_t off_go  = 23019520;   // gcn_out 2.05M
    const size_t off_ctr = 25067520;   // contrib 2.05M
    const size_t base_end = 27115520;
    // split region S (floats): attn_ws 2048000 | w1t 262144 | w2t 131072
    //                          | rnn_nt 4194304 | rnnT 4194304  = 10829824
    const size_t S_sz = 10829824;
    // chunk region (floats): scores/x2 NB*1024000 + attn NB*2048000 + x1 NB*2048000
    const size_t have = ws_size / 4;
    int NB; size_t offS, offC;
    if      (have >= base_end + S_sz + 4ul * 5120000) { NB = 4; offS = base_end; offC = base_end + S_sz; }
    else if (have >= base_end + S_sz + 2ul * 5120000) { NB = 2; offS = base_end; offC = base_end + S_sz; }
    else if (have >= base_end + S_sz)                 { NB = 2; offS = base_end; offC = off_gf; }
    else { NB = 1; offS = off_gf; offC = off_gf + S_sz; }  // floor: 27.1M floats

    float* gates_f = wsf + off_gf;
    float* gates_b = wsf + off_gb;
    float* rnn     = wsf + off_rnn;
    float* gcn_tmp = wsf + off_tmp;
    float* gcn_out = wsf + off_go;
    float* contrib = wsf + off_ctr;
    float* hbuf    = wsf + off_tmp;                  // [2][64][256] overlay
    int*   stamp   = (int*)(wsf + off_tmp + 32768);  // [64][16] overlay

    ushort* attn_ws16 = (ushort*)(wsf + offS);                // [4000][1024]
    ushort* w1t16     = (ushort*)(wsf + offS + 2048000);      // [512][1024]
    ushort* w2t16     = (ushort*)(wsf + offS + 2310144);      // [256][1024]
    ushort* rnn_nt16  = (ushort*)(wsf + offS + 2441216);      // [32][256][1024]
    ushort* rnnT16    = (ushort*)(wsf + offS + 6635520);      // [32][512][512]

    float*  scoresb = wsf + offC;                             // NB*[4000][256] f32 (probs/x2 alias)
    ushort* attn16  = (ushort*)(wsf + offC + (size_t)NB * 1024000);  // NB*[4000][1024]
    ushort* x116    = (ushort*)(wsf + offC + (size_t)NB * 1024000 + (size_t)NB * 2048000);
    float*  x2b     = scoresb;                                // alias (probs dead by then)

    // 0. zero lstm stamps
    init_cnt_k<<<4, 256, 0, stream>>>(stamp);

    // 1. input projections (embedding gather fused)
    gemm_k<true, true><<<dim3(8, 128, 1), 256, 0, stream>>>(
        emb, w_ih_f, gates_f, 8192, 1024, 300, 300, 300, 1024,
        0, 0, 0, tokens, b_f, nullptr, 1, 0, 0);
    gemm_k<true, true><<<dim3(8, 128, 1), 256, 0, stream>>>(
        emb, w_ih_b, gates_b, 8192, 1024, 300, 300, 300, 1024,
        0, 0, 0, tokens, b_b, nullptr, 1, 0, 0);

    // 2. biLSTM scan -> rnn [B,S,512]
    lstm_reg_k<<<dim3(64, 4), 1024, 0, stream>>>(
        gates_f, gates_b, w_hh_f, w_hh_b, rnn, hbuf, stamp);

    // 3. split conversions (after lstm: gates region may be reused in fallback)
    split_k<<<16384, 256, 0, stream>>>(rnn, rnn_nt16, 8192, 512);        // [b*s][2H] -> NT split
    tsplit_k<<<dim3(8, 4, 32), 256, 0, stream>>>(rnn, rnnT16, 256, 512, 512, 131072, 262144);
    split_k<<<8000, 256, 0, stream>>>(attn_w, attn_ws16, 4000, 512);
    tsplit_k<<<dim3(8, 8, 1), 256, 0, stream>>>(w1, w1t16, 512, 512, 512, 0, 0);
    tsplit_k<<<dim3(4, 8, 1), 256, 0, stream>>>(w2, w2t16, 512, 256, 256, 0, 0);

    // 4. GCN branch
    gemm_k<false, false><<<dim3(4, 63, 1), 256, 0, stream>>>(
        label_emb, gcn_w, gcn_tmp, 4000, 512, 256, 256, 512, 512,
        0, 0, 0, nullptr, nullptr, nullptr, 1, 0, 0);
    spmm_k<<<dim3(4000), 256, 0, stream>>>(adj, gcn_tmp, gcn_b, gcn_out);
    gemm_k<false, false><<<dim3(4, 63, 1), 256, 0, stream>>>(
        gcn_out, w1 + (size_t)512 * 512, contrib, 4000, 512, 512, 512, 512, 512,
        0, 0, 0, nullptr, b1, nullptr, 1, 0, 0);

    // 5. attention + MLP head (MFMA split-bf16), chunked over batch
    for (int b0 = 0; b0 < 32; b0 += NB) {
        const int nb = (32 - b0 < NB) ? (32 - b0) : NB;
        // scores[bb,l,s] = attn_w[l,:] . rnn[bb,s,:]
        mgemm_k<false, false, false, true, false><<<dim3(32, 2, nb), 256, 0, stream>>>(
            attn_ws16, rnn_nt16 + (size_t)b0 * 262144, scoresb, nullptr,
            4000, 256, 512, 1024, 1024, 256, 0,
            0L, 262144L, 1024000L, 0L, nullptr, nullptr, 1, 0);
        // softmax + in-place split
        softmax_split_k<<<dim3(1000, nb), 256, 0, stream>>>(scoresb, tokens, b0);
        // attn[bb,l,h] = probs[bb,l,:] . rnnT[bb,h,:]  -> split out
        mgemm_k<false, false, false, false, true><<<dim3(32, 4, nb), 256, 0, stream>>>(
            (const ushort*)scoresb, rnnT16 + (size_t)b0 * 262144, nullptr, attn16,
            4000, 512, 256, 512, 512, 0, 1024,
            2048000L, 262144L, 0L, 4096000L, nullptr, nullptr, 1, 0);
        // x1 = relu(attn @ w1[:512] + contrib)  -> split out
        mgemm_k<false, true, true, false, true><<<dim3((nb * 4000 + 127) / 128, 4, 1), 256, 0, stream>>>(
            attn16, w1t16, nullptr, x116,
            nb * 4000, 512, 512, 1024, 1024, 0, 1024,
            0L, 0L, 0L, 0L, nullptr, contrib, 4000, 512);
        // x2 = relu(x1 @ w2 + b2)  -> fp32 (overlays scores/probs, now dead)
        mgemm_k<true, false, true, true, false><<<dim3((nb * 4000 + 127) / 128, 2, 1), 256, 0, stream>>>(
            x116, w2t16, x2b, nullptr,
            nb * 4000, 256, 512, 1024, 1024, 256, 0,
            0L, 0L, 0L, 0L, b2, nullptr, 1, 0);
        // out = x2 @ w_out + b_out
        out_k<<<dim3(nb * 1000), 256, 0, stream>>>(x2b, w_out, b_out, outp, b0);
    }
}

// Round 6
// 2028.132 us; speedup vs baseline: 3.4513x; 1.4194x over previous
//
#include <hip/hip_runtime.h>
#include <hip/hip_bf16.h>
#include <math.h>

// Problem constants
// B=32 S=256 E=300 H=256(4H=1024) L=4000 D=256 G=512 V=50000 LIN1=512 LIN2=256, 2H=512

typedef __attribute__((ext_vector_type(8))) short bfrag;   // 8 bf16 (4 VGPRs)
typedef __attribute__((ext_vector_type(4))) float ffrag;   // 4 fp32 acc

__device__ __forceinline__ ushort f2bf(float x) {
    union { float f; unsigned u; } c; c.f = x;
    const unsigned r = c.u + 0x7fffu + ((c.u >> 16) & 1u);
    return (ushort)(r >> 16);
}
__device__ __forceinline__ float bf2f(ushort h) {
    union { unsigned u; float f; } c; c.u = (unsigned)h << 16;
    return c.f;
}

// ---------------------------------------------------------------------------
// fp32 tiled GEMM (64x128 tile) -- GCN branch only now.
// ---------------------------------------------------------------------------
template<bool BT, bool GATHER>
__global__ __launch_bounds__(256) void gemm_k(
    const float* __restrict__ A, const float* __restrict__ Bm, float* __restrict__ C,
    int M, int N, int K, int lda, int ldb, int ldc,
    long abs_, long bbs_, long cbs_,
    const int* __restrict__ tok,
    const float* __restrict__ bias,
    const float* __restrict__ addrow, int addmod, int ldadd,
    int do_relu)
{
    const int tid = threadIdx.x;
    const int tx = tid & 15;
    const int ty = tid >> 4;
    const int n0 = blockIdx.x * 128;
    const int m0 = blockIdx.y * 64;
    const int z  = blockIdx.z;
    A  += (size_t)z * abs_;
    Bm += (size_t)z * bbs_;
    C  += (size_t)z * cbs_;

    __shared__ float As[16][68];
    __shared__ float Bs[16][132];

    float acc[4][8];
#pragma unroll
    for (int i = 0; i < 4; ++i)
#pragma unroll
        for (int j = 0; j < 8; ++j) acc[i][j] = 0.f;

    const int ksteps = (K + 15) / 16;
    for (int kt = 0; kt < ksteps; ++kt) {
        const int k0 = kt * 16;
#pragma unroll
        for (int j = 0; j < 4; ++j) {
            int e  = tid + j * 256;
            int kk = e & 15;
            int m  = e >> 4;
            int gm = m0 + m, gk = k0 + kk;
            float v = 0.f;
            if (gm < M && gk < K) {
                size_t rb;
                if (GATHER) rb = (size_t)tok[gm] * lda;
                else        rb = (size_t)gm * lda;
                v = A[rb + gk];
            }
            As[kk][m] = v;
        }
#pragma unroll
        for (int j = 0; j < 8; ++j) {
            int e = tid + j * 256;
            if (BT) {
                int kk = e & 15;
                int n  = e >> 4;
                int gn = n0 + n, gk = k0 + kk;
                Bs[kk][n] = (gn < N && gk < K) ? Bm[(size_t)gn * ldb + gk] : 0.f;
            } else {
                int n  = e & 127;
                int kk = e >> 7;
                int gn = n0 + n, gk = k0 + kk;
                Bs[kk][n] = (gn < N && gk < K) ? Bm[(size_t)gk * ldb + gn] : 0.f;
            }
        }
        __syncthreads();
#pragma unroll
        for (int kk = 0; kk < 16; ++kk) {
            const float4 av  = *(const float4*)&As[kk][ty * 4];
            const float4 b0v = *(const float4*)&Bs[kk][tx * 8];
            const float4 b1v = *(const float4*)&Bs[kk][tx * 8 + 4];
            const float a_[4] = {av.x, av.y, av.z, av.w};
            const float b_[8] = {b0v.x, b0v.y, b0v.z, b0v.w, b1v.x, b1v.y, b1v.z, b1v.w};
#pragma unroll
            for (int i = 0; i < 4; ++i)
#pragma unroll
                for (int j = 0; j < 8; ++j) acc[i][j] = fmaf(a_[i], b_[j], acc[i][j]);
        }
        __syncthreads();
    }

#pragma unroll
    for (int i = 0; i < 4; ++i) {
        const int gm = m0 + ty * 4 + i;
        if (gm >= M) continue;
        const float* addp = addrow ? (addrow + (size_t)(gm % addmod) * ldadd) : nullptr;
#pragma unroll
        for (int j = 0; j < 8; ++j) {
            const int gn = n0 + tx * 8 + j;
            if (gn >= N) continue;
            float v = acc[i][j];
            if (bias) v += bias[gn];
            if (addp) v += addp[gn];
            if (do_relu) v = fmaxf(v, 0.f);
            C[(size_t)gm * ldc + gn] = v;
        }
    }
}

// ---------------------------------------------------------------------------
// Split-bf16 MFMA GEMM: C = A * B^T via 3-term split (hh + hl + lh).
// A: [M][lda] bf16, row = [hi(0..K) | lo(0..K)]; B likewise. Tile 128x128,
// BK=32, 4 waves (2x2 of 64x64). LDS rows padded to 40 bf16 (80B stride).
// ---------------------------------------------------------------------------
template<bool BIAS, bool ADDROW, bool RELU, bool OUTF, bool OUTS>
__global__ __launch_bounds__(256) void mgemm_k(
    const ushort* __restrict__ A, const ushort* __restrict__ B,
    float* __restrict__ Cf, ushort* __restrict__ Cs,
    int M, int N, int K, int lda, int ldb, int ldc, int ldcs,
    long abs_, long bbs_, long cbs_, long csbs_,
    const float* __restrict__ bias,
    const float* __restrict__ addrow, int addmod, int ldadd)
{
    const int tid = threadIdx.x;
    const int ln = tid & 63;
    const int wv = tid >> 6;
    const int wm = wv >> 1, wn = wv & 1;
    const int m0 = blockIdx.x * 128, n0 = blockIdx.y * 128;
    const int z = blockIdx.z;
    A += (size_t)z * abs_;
    B += (size_t)z * bbs_;

    __shared__ ushort Ah[128 * 40], Al[128 * 40], Bh[128 * 40], Bl[128 * 40];

    ffrag acc[4][4];
#pragma unroll
    for (int i = 0; i < 4; ++i)
#pragma unroll
        for (int j = 0; j < 4; ++j) acc[i][j] = ffrag{0.f, 0.f, 0.f, 0.f};

    const int sr = tid >> 1;
    const int sk = (tid & 1) * 16;
    const int am = min(m0 + sr, M - 1);
    const int bn = n0 + sr;
    const int fr = ln & 15;
    const int fk = (ln >> 4) * 8;

    const ushort* arow = A + (size_t)am * lda;
    const ushort* brow = B + (size_t)bn * ldb;

    for (int k0 = 0; k0 < K; k0 += 32) {
        const ushort* ap = arow + k0 + sk;
        const ushort* bp = brow + k0 + sk;
        const bfrag ah0 = *(const bfrag*)ap;
        const bfrag ah1 = *(const bfrag*)(ap + 8);
        const bfrag al0 = *(const bfrag*)(ap + K);
        const bfrag al1 = *(const bfrag*)(ap + K + 8);
        const bfrag bh0 = *(const bfrag*)bp;
        const bfrag bh1 = *(const bfrag*)(bp + 8);
        const bfrag bl0 = *(const bfrag*)(bp + K);
        const bfrag bl1 = *(const bfrag*)(bp + K + 8);
        __syncthreads();
        *(bfrag*)&Ah[sr * 40 + sk] = ah0;  *(bfrag*)&Ah[sr * 40 + sk + 8] = ah1;
        *(bfrag*)&Al[sr * 40 + sk] = al0;  *(bfrag*)&Al[sr * 40 + sk + 8] = al1;
        *(bfrag*)&Bh[sr * 40 + sk] = bh0;  *(bfrag*)&Bh[sr * 40 + sk + 8] = bh1;
        *(bfrag*)&Bl[sr * 40 + sk] = bl0;  *(bfrag*)&Bl[sr * 40 + sk + 8] = bl1;
        __syncthreads();
        bfrag afh[4], afl[4], bfh[4], bfl[4];
#pragma unroll
        for (int i = 0; i < 4; ++i) {
            const int ar = (wm * 64 + i * 16 + fr) * 40 + fk;
            const int br = (wn * 64 + i * 16 + fr) * 40 + fk;
            afh[i] = *(const bfrag*)&Ah[ar];
            afl[i] = *(const bfrag*)&Al[ar];
            bfh[i] = *(const bfrag*)&Bh[br];
            bfl[i] = *(const bfrag*)&Bl[br];
        }
#pragma unroll
        for (int i = 0; i < 4; ++i)
#pragma unroll
            for (int j = 0; j < 4; ++j) {
                acc[i][j] = __builtin_amdgcn_mfma_f32_16x16x32_bf16(afh[i], bfh[j], acc[i][j], 0, 0, 0);
                acc[i][j] = __builtin_amdgcn_mfma_f32_16x16x32_bf16(afh[i], bfl[j], acc[i][j], 0, 0, 0);
                acc[i][j] = __builtin_amdgcn_mfma_f32_16x16x32_bf16(afl[i], bfh[j], acc[i][j], 0, 0, 0);
            }
    }

#pragma unroll
    for (int i = 0; i < 4; ++i) {
#pragma unroll
        for (int rg = 0; rg < 4; ++rg) {
            const int gm = m0 + wm * 64 + i * 16 + (ln >> 4) * 4 + rg;
            if (gm >= M) continue;
            const float* addp = ADDROW ? (addrow + (size_t)(gm % addmod) * ldadd) : nullptr;
#pragma unroll
            for (int j = 0; j < 4; ++j) {
                const int gn = n0 + wn * 64 + j * 16 + fr;
                float v = acc[i][j][rg];
                if (BIAS) v += bias[gn];
                if (ADDROW) v += addp[gn];
                if (RELU) v = fmaxf(v, 0.f);
                if (OUTF) Cf[(size_t)z * cbs_ + (size_t)gm * ldc + gn] = v;
                if (OUTS) {
                    const ushort h = f2bf(v);
                    const ushort l = f2bf(v - bf2f(h));
                    ushort* cp = Cs + (size_t)z * csbs_ + (size_t)gm * ldcs;
                    cp[gn] = h;
                    cp[N + gn] = l;
                }
            }
        }
    }
}

// ---------------------------------------------------------------------------
// Gather(optional) + split + zero-pad: row r of src (K cols) -> [r][2*Kpad]
// ---------------------------------------------------------------------------
__global__ void gsplit_k(const float* __restrict__ src, const int* __restrict__ tok,
                         ushort* __restrict__ outp, int K, int Kpad)
{
    const int r = blockIdx.x;
    const float* s = src + (size_t)(tok ? tok[r] : r) * K;
    ushort* o = outp + (size_t)r * 2 * Kpad;
    for (int k = threadIdx.x; k < Kpad; k += blockDim.x) {
        const float x = (k < K) ? s[k] : 0.f;
        const ushort h = f2bf(x);
        const ushort l = f2bf(x - bf2f(h));
        o[k] = h;
        o[Kpad + k] = l;
    }
}

// ---------------------------------------------------------------------------
// fp32 [rows][K] -> split bf16 [rows][2K] (hi | lo)
// ---------------------------------------------------------------------------
__global__ void split_k(const float* __restrict__ in, ushort* __restrict__ outp,
                        int rows, int K)
{
    const int i = blockIdx.x * 256 + threadIdx.x;
    if (i >= rows * K) return;
    const int r = i / K, k = i - r * K;
    const float x = in[i];
    const ushort h = f2bf(x);
    const ushort l = f2bf(x - bf2f(h));
    ushort* o = outp + (size_t)r * 2 * K;
    o[k] = h;
    o[K + k] = l;
}

// ---------------------------------------------------------------------------
// fp32 [R][C] -> split-transposed bf16 [C][2R]
// ---------------------------------------------------------------------------
__global__ __launch_bounds__(256) void tsplit_k(
    const float* __restrict__ in, ushort* __restrict__ outp,
    int R, int C, int ldin, long ibs, long obs)
{
    __shared__ float t[64][65];
    const int c0 = blockIdx.x * 64, r0 = blockIdx.y * 64;
    in   += (size_t)blockIdx.z * ibs;
    outp += (size_t)blockIdx.z * obs;
    const int tx = threadIdx.x & 15, ty = threadIdx.x >> 4;
#pragma unroll
    for (int i = 0; i < 4; ++i) {
        const int r = ty * 4 + i;
        const float4 v = *(const float4*)&in[(size_t)(r0 + r) * ldin + c0 + tx * 4];
        t[tx * 4 + 0][r] = v.x;
        t[tx * 4 + 1][r] = v.y;
        t[tx * 4 + 2][r] = v.z;
        t[tx * 4 + 3][r] = v.w;
    }
    __syncthreads();
    const int R2 = 2 * R;
#pragma unroll
    for (int i = 0; i < 4; ++i) {
        const int c = ty * 4 + i;
        ushort h[4], l[4];
#pragma unroll
        for (int k2 = 0; k2 < 4; ++k2) {
            const float x = t[c][tx * 4 + k2];
            h[k2] = f2bf(x);
            l[k2] = f2bf(x - bf2f(h[k2]));
        }
        uint2 hw, lw;
        hw.x = (unsigned)h[0] | ((unsigned)h[1] << 16);
        hw.y = (unsigned)h[2] | ((unsigned)h[3] << 16);
        lw.x = (unsigned)l[0] | ((unsigned)l[1] << 16);
        lw.y = (unsigned)l[2] | ((unsigned)l[3] << 16);
        *(uint2*)&outp[(size_t)(c0 + c) * R2 + r0 + tx * 4] = hw;
        *(uint2*)&outp[(size_t)(c0 + c) * R2 + R + r0 + tx * 4] = lw;
    }
}

// ---------------------------------------------------------------------------
// Register-resident biLSTM scan v4: atomics-only protocol (NO acquire fence --
// all cross-block data moves via agent-scope atomics, which bypass the
// non-coherent per-XCD L2s; the R5 fence emitted a per-step L2 invalidate).
// Activation parallelized across all 16 waves via in-wave shfl (4 units/wave).
// Stamp release: __syncthreads drains every wave's h-stores (vmcnt(0) per
// wave before s_barrier), then tid0's relaxed stamp store is safely ordered.
// ---------------------------------------------------------------------------
__global__ __launch_bounds__(1024) void lstm_reg_k(
    const float* __restrict__ gxf, const float* __restrict__ gxb,
    const float* __restrict__ whf, const float* __restrict__ whb,
    float* __restrict__ rnn, float* hbuf, int* stamp)
{
    const int p = blockIdx.x;          // pair: batch b=p>>1, dir=p&1
    const int q = blockIdx.y;          // quarter (owns units [64q,64q+64))
    const int b = p >> 1, dir = p & 1;
    const float* xg = dir ? gxb : gxf;
    const float* W  = dir ? whb : whf;
    const int tid = threadIdx.x;
    const int wv = tid >> 6, lane = tid & 63;
    const int ul = lane >> 4;           // unit-local 0..3
    const int u  = wv * 4 + ul;         // block unit 0..63
    const int gt = (lane >> 2) & 3;     // gate 0..3
    const int ks = lane & 3;            // 64-float k-slice
    const int grow = gt * 256 + q * 64 + u;

    float4 w[16];
    {
        const float4* wp = (const float4*)(W + (size_t)grow * 256 + ks * 64);
#pragma unroll
        for (int i = 0; i < 16; ++i) w[i] = wp[i];
    }

    __shared__ float h_lds[4 * 68];
    __shared__ float xg_lds[256];

    float* hb0 = hbuf + (size_t)p * 256;            // parity 0
    float* hb1 = hbuf + (size_t)(64 + p) * 256;     // parity 1
    int* sp = stamp + p * 16;

    const size_t xgb = (size_t)b * 256;
    const int g2 = (tid >> 6) * 256 + q * 64 + (tid & 63);  // staging map (tid<256)
    float c = 0.f;                                   // live in lanes (lane&15)==0
    float xg_cur = 0.f;
    if (tid < 256) xg_cur = xg[(xgb + (dir ? 255 : 0)) * 1024 + g2];

    for (int st = 0; st < 256; ++st) {
        const int ts = dir ? 255 - st : st;
        if (st > 0 && tid == 0) {
            while (true) {
                int s0 = __hip_atomic_load(&sp[0], __ATOMIC_RELAXED, __HIP_MEMORY_SCOPE_AGENT);
                int s1 = __hip_atomic_load(&sp[1], __ATOMIC_RELAXED, __HIP_MEMORY_SCOPE_AGENT);
                int s2 = __hip_atomic_load(&sp[2], __ATOMIC_RELAXED, __HIP_MEMORY_SCOPE_AGENT);
                int s3 = __hip_atomic_load(&sp[3], __ATOMIC_RELAXED, __HIP_MEMORY_SCOPE_AGENT);
                if (min(min(s0, s1), min(s2, s3)) >= st) break;
            }
        }
        __syncthreads();   // B1: partners' h[st-1] published (via atomics)
        if (tid < 256) {
            float hv = 0.f;
            if (st > 0) {
                const float* src = (st & 1) ? hb0 : hb1;   // parity (st-1)&1
                hv = __hip_atomic_load(&src[tid], __ATOMIC_RELAXED, __HIP_MEMORY_SCOPE_AGENT);
            }
            h_lds[(tid >> 6) * 68 + (tid & 63)] = hv;
            xg_lds[tid] = xg_cur;
        }
        __syncthreads();   // B2: h_lds/xg_lds ready
        float acc = 0.f;
        {
            const float4* hp = (const float4*)&h_lds[ks * 68];
#pragma unroll
            for (int i = 0; i < 16; ++i) {
                const float4 hv = hp[i];
                acc = fmaf(w[i].x, hv.x, acc);
                acc = fmaf(w[i].y, hv.y, acc);
                acc = fmaf(w[i].z, hv.z, acc);
                acc = fmaf(w[i].w, hv.w, acc);
            }
        }
        acc += __shfl_xor(acc, 1);
        acc += __shfl_xor(acc, 2);
        const float g = acc + xg_lds[gt * 64 + u];   // full gate pre-act (all ks lanes)
        const int base = ul * 16;                    // lane of (u, gt=0, ks=0)
        const float gi = __shfl(g, base);
        const float gf = __shfl(g, base + 4);
        const float gg = __shfl(g, base + 8);
        const float go = __shfl(g, base + 12);
        if ((lane & 15) == 0) {                      // 4 act lanes per wave
            const float si = 1.f / (1.f + __expf(-gi));
            const float sf = 1.f / (1.f + __expf(-gf));
            const float so = 1.f / (1.f + __expf(-go));
            const float tg = 1.f - 2.f / (__expf(2.f * gg) + 1.f);
            c = sf * c + si * tg;
            const float tc = 1.f - 2.f / (__expf(2.f * c) + 1.f);
            const float hn = so * tc;
            float* dst = (st & 1) ? hb1 : hb0;       // parity st&1
            __hip_atomic_store(&dst[q * 64 + u], hn, __ATOMIC_RELAXED, __HIP_MEMORY_SCOPE_AGENT);
            rnn[(xgb + ts) * 512 + (size_t)dir * 256 + q * 64 + u] = hn;
        }
        __syncthreads();   // B3: every wave drains vmcnt(0) -> all h stores acked
        if (tid == 0) {
            __hip_atomic_store(&sp[q], st + 1, __ATOMIC_RELAXED, __HIP_MEMORY_SCOPE_AGENT);
        }
        // prefetch next step's xg (off critical path)
        if (tid < 256 && st < 255) {
            const int tsn = dir ? 254 - st : st + 1;
            xg_cur = xg[(xgb + tsn) * 1024 + g2];
        }
    }
}

__global__ void init_cnt_k(int* stamp) {
    const int i = blockIdx.x * blockDim.x + threadIdx.x;
    if (i < 1024) stamp[i] = 0;
}

// ---------------------------------------------------------------------------
// Masked softmax over s (256); writes split-bf16 probs in place.
// ---------------------------------------------------------------------------
__global__ __launch_bounds__(256) void softmax_split_k(
    float* __restrict__ sc, const int* __restrict__ tokens, int b0)
{
    const int bb = blockIdx.y;
    const int l  = blockIdx.x * 4 + (threadIdx.x >> 6);
    const int lane = threadIdx.x & 63;
    float* row = sc + ((size_t)bb * 4000 + l) * 256;
    const int* tk = tokens + (size_t)(b0 + bb) * 256;
    float4 v = *(const float4*)&row[lane * 4];
    const int4 tv = *(const int4*)&tk[lane * 4];
    if (tv.x == 0) v.x = -1e9f;
    if (tv.y == 0) v.y = -1e9f;
    if (tv.z == 0) v.z = -1e9f;
    if (tv.w == 0) v.w = -1e9f;
    float mx = fmaxf(fmaxf(v.x, v.y), fmaxf(v.z, v.w));
    for (int o = 32; o > 0; o >>= 1) mx = fmaxf(mx, __shfl_xor(mx, o));
    v.x = __expf(v.x - mx); v.y = __expf(v.y - mx);
    v.z = __expf(v.z - mx); v.w = __expf(v.w - mx);
    float s = v.x + v.y + v.z + v.w;
    for (int o = 32; o > 0; o >>= 1) s += __shfl_xor(s, o);
    const float inv = 1.f / s;
    const float p0 = v.x * inv, p1 = v.y * inv, p2 = v.z * inv, p3 = v.w * inv;
    const ushort h0 = f2bf(p0), h1 = f2bf(p1), h2 = f2bf(p2), h3 = f2bf(p3);
    const ushort l0 = f2bf(p0 - bf2f(h0)), l1 = f2bf(p1 - bf2f(h1));
    const ushort l2 = f2bf(p2 - bf2f(h2)), l3 = f2bf(p3 - bf2f(h3));
    ushort* orow = (ushort*)row;
    uint2 hw, lw;
    hw.x = (unsigned)h0 | ((unsigned)h1 << 16);
    hw.y = (unsigned)h2 | ((unsigned)h3 << 16);
    lw.x = (unsigned)l0 | ((unsigned)l1 << 16);
    lw.y = (unsigned)l2 | ((unsigned)l3 << 16);
    *(uint2*)&orow[lane * 4] = hw;
    *(uint2*)&orow[256 + lane * 4] = lw;
}

// ---------------------------------------------------------------------------
// Sparse GCN aggregation.
// ---------------------------------------------------------------------------
__global__ __launch_bounds__(256) void spmm_k(
    const float* __restrict__ adj, const float* __restrict__ tmp,
    const float* __restrict__ bias, float* __restrict__ outp)
{
    const int l = blockIdx.x;
    __shared__ int   idxs[4][256];
    __shared__ float vals[4][256];
    __shared__ int   cnts[4];
    const int t = threadIdx.x;
    const int w = t >> 6, lane = t & 63;
    const float* arow = adj + (size_t)l * 4000;
    int cnt = 0;
    for (int r = 0; r < 16; ++r) {
        const int o = r * 64 + lane;
        const int j = w * 1000 + o;
        const float a = (o < 1000) ? arow[j] : 0.f;
        const unsigned long long mk = __ballot(a != 0.f);
        if (a != 0.f) {
            const int pos = cnt + __popcll(mk & ((1ull << lane) - 1ull));
            if (pos < 256) { idxs[w][pos] = j; vals[w][pos] = a; }
        }
        cnt += __popcll(mk);
    }
    if (lane == 0) cnts[w] = min(cnt, 256);
    __syncthreads();
    const int c0 = t * 2;
    float a0 = 0.f, a1 = 0.f;
    for (int ww = 0; ww < 4; ++ww) {
        const int n = cnts[ww];
        for (int e = 0; e < n; ++e) {
            const float a = vals[ww][e];
            const float2 tv = *(const float2*)&tmp[(size_t)idxs[ww][e] * 512 + c0];
            a0 = fmaf(a, tv.x, a0);
            a1 = fmaf(a, tv.y, a1);
        }
    }
    float2 res;
    res.x = fmaxf(a0 + bias[c0], 0.f);
    res.y = fmaxf(a1 + bias[c0 + 1], 0.f);
    *(float2*)&outp[(size_t)l * 512 + c0] = res;
}

// ---------------------------------------------------------------------------
// Final projection.
// ---------------------------------------------------------------------------
__global__ __launch_bounds__(256) void out_k(
    const float* __restrict__ x2, const float* __restrict__ w_out,
    const float* __restrict__ b_out, float* __restrict__ outp, int b0)
{
    const int r = blockIdx.x * 4 + (threadIdx.x >> 6);
    const int lane = threadIdx.x & 63;
    const float4 xv = *(const float4*)&x2[(size_t)r * 256 + lane * 4];
    const float4 wv = *(const float4*)&w_out[lane * 4];
    float s = xv.x * wv.x + xv.y * wv.y + xv.z * wv.z + xv.w * wv.w;
    for (int o = 32; o > 0; o >>= 1) s += __shfl_xor(s, o);
    if (lane == 0) {
        const int bb = r / 4000, l = r - bb * 4000;
        outp[(size_t)(b0 + bb) * 4000 + l] = s + b_out[0];
    }
}

// ---------------------------------------------------------------------------
extern "C" void kernel_launch(void* const* d_in, const int* in_sizes, int n_in,
                              void* d_out, int out_size, void* d_ws, size_t ws_size,
                              hipStream_t stream)
{
    const int*   tokens    = (const int*)  d_in[0];
    const float* emb       = (const float*)d_in[1];
    const float* w_ih_f    = (const float*)d_in[2];
    const float* w_hh_f    = (const float*)d_in[3];
    const float* b_f       = (const float*)d_in[4];
    const float* w_ih_b    = (const float*)d_in[5];
    const float* w_hh_b    = (const float*)d_in[6];
    const float* b_b       = (const float*)d_in[7];
    const float* attn_w    = (const float*)d_in[8];
    const float* label_emb = (const float*)d_in[9];
    const float* adj       = (const float*)d_in[10];
    const float* gcn_w     = (const float*)d_in[11];
    const float* gcn_b     = (const float*)d_in[12];
    const float* w1        = (const float*)d_in[13];
    const float* b1        = (const float*)d_in[14];
    const float* w2        = (const float*)d_in[15];
    const float* b2        = (const float*)d_in[16];
    const float* w_out     = (const float*)d_in[17];
    const float* b_out     = (const float*)d_in[18];
    float* outp = (float*)d_out;
    float* wsf  = (float*)d_ws;

    // ---- workspace layout (float offsets) ----
    const size_t off_gf  = 0;          // gates_f 8.39M
    const size_t off_gb  = 8388608;    // gates_b 8.39M
    const size_t off_rnn = 16777216;   // rnn fp32 4.19M
    const size_t off_tmp = 20971520;   // gcn_tmp 2.05M (lstm hbuf/stamp overlay)
    const size_t off_go  = 23019520;   // gcn_out 2.05M
    const size_t off_ctr = 25067520;   // contrib 2.05M
    const size_t base_end = 27115520;
    const size_t S_sz = 10829824;
    const size_t have = ws_size / 4;
    int NB; size_t offS, offC;
    if      (have >= base_end + S_sz + 4ul * 5120000) { NB = 4; offS = base_end; offC = base_end + S_sz; }
    else if (have >= base_end + S_sz + 2ul * 5120000) { NB = 2; offS = base_end; offC = base_end + S_sz; }
    else if (have >= base_end + S_sz)                 { NB = 2; offS = base_end; offC = off_gf; }
    else { NB = 1; offS = off_gf; offC = off_gf + S_sz; }

    float* gates_f = wsf + off_gf;
    float* gates_b = wsf + off_gb;
    float* rnn     = wsf + off_rnn;
    float* gcn_tmp = wsf + off_tmp;
    float* gcn_out = wsf + off_go;
    float* contrib = wsf + off_ctr;
    float* hbuf    = wsf + off_tmp;                  // [2][64][256] overlay
    int*   stamp   = (int*)(wsf + off_tmp + 32768);  // [64][16] overlay

    // pre-lstm split staging (dead by the time its host region is reused):
    // esplit [8192][640]u + wsplitf/b [1024][640]u each = 3,276,800 floats
    const size_t off_esp = (offS == off_gf) ? off_rnn : offS;
    ushort* esplit  = (ushort*)(wsf + off_esp);
    ushort* wsplitf = esplit + (size_t)8192 * 640;
    ushort* wsplitb = wsplitf + (size_t)1024 * 640;

    ushort* attn_ws16 = (ushort*)(wsf + offS);                // [4000][1024]
    ushort* w1t16     = (ushort*)(wsf + offS + 2048000);      // [512][1024]
    ushort* w2t16     = (ushort*)(wsf + offS + 2310144);      // [256][1024]
    ushort* rnn_nt16  = (ushort*)(wsf + offS + 2441216);      // [32][256][1024]
    ushort* rnnT16    = (ushort*)(wsf + offS + 6635520);      // [32][512][512]

    float*  scoresb = wsf + offC;
    ushort* attn16  = (ushort*)(wsf + offC + (size_t)NB * 1024000);
    ushort* x116    = (ushort*)(wsf + offC + (size_t)NB * 1024000 + (size_t)NB * 2048000);
    float*  x2b     = scoresb;

    // 0. zero lstm stamps
    init_cnt_k<<<4, 256, 0, stream>>>(stamp);

    // 1. input projections on MFMA: gather+split emb / w_ih, then split GEMM
    gsplit_k<<<8192, 256, 0, stream>>>(emb, tokens, esplit, 300, 320);
    gsplit_k<<<1024, 256, 0, stream>>>(w_ih_f, nullptr, wsplitf, 300, 320);
    gsplit_k<<<1024, 256, 0, stream>>>(w_ih_b, nullptr, wsplitb, 300, 320);
    mgemm_k<true, false, false, true, false><<<dim3(64, 8, 1), 256, 0, stream>>>(
        esplit, wsplitf, gates_f, nullptr,
        8192, 1024, 320, 640, 640, 1024, 0,
        0L, 0L, 0L, 0L, b_f, nullptr, 1, 0);
    mgemm_k<true, false, false, true, false><<<dim3(64, 8, 1), 256, 0, stream>>>(
        esplit, wsplitb, gates_b, nullptr,
        8192, 1024, 320, 640, 640, 1024, 0,
        0L, 0L, 0L, 0L, b_b, nullptr, 1, 0);

    // 2. biLSTM scan -> rnn [B,S,512]
    lstm_reg_k<<<dim3(64, 4), 1024, 0, stream>>>(
        gates_f, gates_b, w_hh_f, w_hh_b, rnn, hbuf, stamp);

    // 3. split conversions for the head
    split_k<<<16384, 256, 0, stream>>>(rnn, rnn_nt16, 8192, 512);
    tsplit_k<<<dim3(8, 4, 32), 256, 0, stream>>>(rnn, rnnT16, 256, 512, 512, 131072, 262144);
    split_k<<<8000, 256, 0, stream>>>(attn_w, attn_ws16, 4000, 512);
    tsplit_k<<<dim3(8, 8, 1), 256, 0, stream>>>(w1, w1t16, 512, 512, 512, 0, 0);
    tsplit_k<<<dim3(4, 8, 1), 256, 0, stream>>>(w2, w2t16, 512, 256, 256, 0, 0);

    // 4. GCN branch
    gemm_k<false, false><<<dim3(4, 63, 1), 256, 0, stream>>>(
        label_emb, gcn_w, gcn_tmp, 4000, 512, 256, 256, 512, 512,
        0, 0, 0, nullptr, nullptr, nullptr, 1, 0, 0);
    spmm_k<<<dim3(4000), 256, 0, stream>>>(adj, gcn_tmp, gcn_b, gcn_out);
    gemm_k<false, false><<<dim3(4, 63, 1), 256, 0, stream>>>(
        gcn_out, w1 + (size_t)512 * 512, contrib, 4000, 512, 512, 512, 512, 512,
        0, 0, 0, nullptr, b1, nullptr, 1, 0, 0);

    // 5. attention + MLP head (MFMA split-bf16), chunked over batch
    for (int b0 = 0; b0 < 32; b0 += NB) {
        const int nb = (32 - b0 < NB) ? (32 - b0) : NB;
        mgemm_k<false, false, false, true, false><<<dim3(32, 2, nb), 256, 0, stream>>>(
            attn_ws16, rnn_nt16 + (size_t)b0 * 262144, scoresb, nullptr,
            4000, 256, 512, 1024, 1024, 256, 0,
            0L, 262144L, 1024000L, 0L, nullptr, nullptr, 1, 0);
        softmax_split_k<<<dim3(1000, nb), 256, 0, stream>>>(scoresb, tokens, b0);
        mgemm_k<false, false, false, false, true><<<dim3(32, 4, nb), 256, 0, stream>>>(
            (const ushort*)scoresb, rnnT16 + (size_t)b0 * 262144, nullptr, attn16,
            4000, 512, 256, 512, 512, 0, 1024,
            2048000L, 262144L, 0L, 4096000L, nullptr, nullptr, 1, 0);
        mgemm_k<false, true, true, false, true><<<dim3((nb * 4000 + 127) / 128, 4, 1), 256, 0, stream>>>(
            attn16, w1t16, nullptr, x116,
            nb * 4000, 512, 512, 1024, 1024, 0, 1024,
            0L, 0L, 0L, 0L, nullptr, contrib, 4000, 512);
        mgemm_k<true, false, true, true, false><<<dim3((nb * 4000 + 127) / 128, 2, 1), 256, 0, stream>>>(
            x116, w2t16, x2b, nullptr,
            nb * 4000, 256, 512, 1024, 1024, 256, 0,
            0L, 0L, 0L, 0L, b2, nullptr, 1, 0);
        out_k<<<dim3(nb * 1000), 256, 0, stream>>>(x2b, w_out, b_out, outp, b0);
    }
}

// Round 7
// 1966.828 us; speedup vs baseline: 3.5589x; 1.0312x over previous
//
#include <hip/hip_runtime.h>
#include <hip/hip_bf16.h>
#include <math.h>

// Problem constants
// B=32 S=256 E=300 H=256(4H=1024) L=4000 D=256 G=512 V=50000 LIN1=512 LIN2=256, 2H=512

typedef __attribute__((ext_vector_type(8))) short bfrag;   // 8 bf16 (4 VGPRs)
typedef __attribute__((ext_vector_type(4))) float ffrag;   // 4 fp32 acc

__device__ __forceinline__ ushort f2bf(float x) {
    union { float f; unsigned u; } c; c.f = x;
    const unsigned r = c.u + 0x7fffu + ((c.u >> 16) & 1u);
    return (ushort)(r >> 16);
}
__device__ __forceinline__ float bf2f(ushort h) {
    union { unsigned u; float f; } c; c.u = (unsigned)h << 16;
    return c.f;
}

// ---------------------------------------------------------------------------
// fp32 tiled GEMM (64x128 tile) -- GCN branch only.
// ---------------------------------------------------------------------------
template<bool BT, bool GATHER>
__global__ __launch_bounds__(256) void gemm_k(
    const float* __restrict__ A, const float* __restrict__ Bm, float* __restrict__ C,
    int M, int N, int K, int lda, int ldb, int ldc,
    long abs_, long bbs_, long cbs_,
    const int* __restrict__ tok,
    const float* __restrict__ bias,
    const float* __restrict__ addrow, int addmod, int ldadd,
    int do_relu)
{
    const int tid = threadIdx.x;
    const int tx = tid & 15;
    const int ty = tid >> 4;
    const int n0 = blockIdx.x * 128;
    const int m0 = blockIdx.y * 64;
    const int z  = blockIdx.z;
    A  += (size_t)z * abs_;
    Bm += (size_t)z * bbs_;
    C  += (size_t)z * cbs_;

    __shared__ float As[16][68];
    __shared__ float Bs[16][132];

    float acc[4][8];
#pragma unroll
    for (int i = 0; i < 4; ++i)
#pragma unroll
        for (int j = 0; j < 8; ++j) acc[i][j] = 0.f;

    const int ksteps = (K + 15) / 16;
    for (int kt = 0; kt < ksteps; ++kt) {
        const int k0 = kt * 16;
#pragma unroll
        for (int j = 0; j < 4; ++j) {
            int e  = tid + j * 256;
            int kk = e & 15;
            int m  = e >> 4;
            int gm = m0 + m, gk = k0 + kk;
            float v = 0.f;
            if (gm < M && gk < K) {
                size_t rb;
                if (GATHER) rb = (size_t)tok[gm] * lda;
                else        rb = (size_t)gm * lda;
                v = A[rb + gk];
            }
            As[kk][m] = v;
        }
#pragma unroll
        for (int j = 0; j < 8; ++j) {
            int e = tid + j * 256;
            if (BT) {
                int kk = e & 15;
                int n  = e >> 4;
                int gn = n0 + n, gk = k0 + kk;
                Bs[kk][n] = (gn < N && gk < K) ? Bm[(size_t)gn * ldb + gk] : 0.f;
            } else {
                int n  = e & 127;
                int kk = e >> 7;
                int gn = n0 + n, gk = k0 + kk;
                Bs[kk][n] = (gn < N && gk < K) ? Bm[(size_t)gk * ldb + gn] : 0.f;
            }
        }
        __syncthreads();
#pragma unroll
        for (int kk = 0; kk < 16; ++kk) {
            const float4 av  = *(const float4*)&As[kk][ty * 4];
            const float4 b0v = *(const float4*)&Bs[kk][tx * 8];
            const float4 b1v = *(const float4*)&Bs[kk][tx * 8 + 4];
            const float a_[4] = {av.x, av.y, av.z, av.w};
            const float b_[8] = {b0v.x, b0v.y, b0v.z, b0v.w, b1v.x, b1v.y, b1v.z, b1v.w};
#pragma unroll
            for (int i = 0; i < 4; ++i)
#pragma unroll
                for (int j = 0; j < 8; ++j) acc[i][j] = fmaf(a_[i], b_[j], acc[i][j]);
        }
        __syncthreads();
    }

#pragma unroll
    for (int i = 0; i < 4; ++i) {
        const int gm = m0 + ty * 4 + i;
        if (gm >= M) continue;
        const float* addp = addrow ? (addrow + (size_t)(gm % addmod) * ldadd) : nullptr;
#pragma unroll
        for (int j = 0; j < 8; ++j) {
            const int gn = n0 + tx * 8 + j;
            if (gn >= N) continue;
            float v = acc[i][j];
            if (bias) v += bias[gn];
            if (addp) v += addp[gn];
            if (do_relu) v = fmaxf(v, 0.f);
            C[(size_t)gm * ldc + gn] = v;
        }
    }
}

// ---------------------------------------------------------------------------
// Split-bf16 MFMA GEMM: C = A * B^T via 3-term split (hh + hl + lh).
// Pipeline: loads for k+1 issued BEFORE the MFMA phase of k (latency hides
// under MFMA); consumed by the ds_write of the next iteration. Single LDS
// buffer (no occupancy cost); 2 barriers/K-step.
// ---------------------------------------------------------------------------
template<bool BIAS, bool ADDROW, bool RELU, bool OUTF, bool OUTS>
__global__ __launch_bounds__(256) void mgemm_k(
    const ushort* __restrict__ A, const ushort* __restrict__ B,
    float* __restrict__ Cf, ushort* __restrict__ Cs,
    int M, int N, int K, int lda, int ldb, int ldc, int ldcs,
    long abs_, long bbs_, long cbs_, long csbs_,
    const float* __restrict__ bias,
    const float* __restrict__ addrow, int addmod, int ldadd)
{
    const int tid = threadIdx.x;
    const int ln = tid & 63;
    const int wv = tid >> 6;
    const int wm = wv >> 1, wn = wv & 1;
    const int m0 = blockIdx.x * 128, n0 = blockIdx.y * 128;
    const int z = blockIdx.z;
    A += (size_t)z * abs_;
    B += (size_t)z * bbs_;

    __shared__ ushort Ah[128 * 40], Al[128 * 40], Bh[128 * 40], Bl[128 * 40];

    ffrag acc[4][4];
#pragma unroll
    for (int i = 0; i < 4; ++i)
#pragma unroll
        for (int j = 0; j < 4; ++j) acc[i][j] = ffrag{0.f, 0.f, 0.f, 0.f};

    const int sr = tid >> 1;
    const int sk = (tid & 1) * 16;
    const int am = min(m0 + sr, M - 1);
    const int bn = n0 + sr;
    const int fr = ln & 15;
    const int fk = (ln >> 4) * 8;

    const ushort* arow = A + (size_t)am * lda + sk;
    const ushort* brow = B + (size_t)bn * ldb + sk;

    bfrag ah0, ah1, al0, al1, bh0, bh1, bl0, bl1;
    // prologue: issue loads for k0 = 0
    {
        const ushort* ap = arow;
        const ushort* bp = brow;
        ah0 = *(const bfrag*)ap;       ah1 = *(const bfrag*)(ap + 8);
        al0 = *(const bfrag*)(ap + K); al1 = *(const bfrag*)(ap + K + 8);
        bh0 = *(const bfrag*)bp;       bh1 = *(const bfrag*)(bp + 8);
        bl0 = *(const bfrag*)(bp + K); bl1 = *(const bfrag*)(bp + K + 8);
    }

    for (int k0 = 0; k0 < K; k0 += 32) {
        __syncthreads();   // previous iteration's frag reads complete
        *(bfrag*)&Ah[sr * 40 + sk] = ah0;  *(bfrag*)&Ah[sr * 40 + sk + 8] = ah1;
        *(bfrag*)&Al[sr * 40 + sk] = al0;  *(bfrag*)&Al[sr * 40 + sk + 8] = al1;
        *(bfrag*)&Bh[sr * 40 + sk] = bh0;  *(bfrag*)&Bh[sr * 40 + sk + 8] = bh1;
        *(bfrag*)&Bl[sr * 40 + sk] = bl0;  *(bfrag*)&Bl[sr * 40 + sk + 8] = bl1;
        __syncthreads();   // tile staged
        if (k0 + 32 < K) {  // issue next-tile loads early: latency hides under MFMA
            const ushort* ap = arow + k0 + 32;
            const ushort* bp = brow + k0 + 32;
            ah0 = *(const bfrag*)ap;       ah1 = *(const bfrag*)(ap + 8);
            al0 = *(const bfrag*)(ap + K); al1 = *(const bfrag*)(ap + K + 8);
            bh0 = *(const bfrag*)bp;       bh1 = *(const bfrag*)(bp + 8);
            bl0 = *(const bfrag*)(bp + K); bl1 = *(const bfrag*)(bp + K + 8);
        }
        bfrag afh[4], afl[4];
#pragma unroll
        for (int i = 0; i < 4; ++i) {
            const int ar = (wm * 64 + i * 16 + fr) * 40 + fk;
            afh[i] = *(const bfrag*)&Ah[ar];
            afl[i] = *(const bfrag*)&Al[ar];
        }
#pragma unroll
        for (int j = 0; j < 4; ++j) {
            const int br = (wn * 64 + j * 16 + fr) * 40 + fk;
            const bfrag bfh = *(const bfrag*)&Bh[br];
            const bfrag bfl = *(const bfrag*)&Bl[br];
#pragma unroll
            for (int i = 0; i < 4; ++i) {
                acc[i][j] = __builtin_amdgcn_mfma_f32_16x16x32_bf16(afh[i], bfh, acc[i][j], 0, 0, 0);
                acc[i][j] = __builtin_amdgcn_mfma_f32_16x16x32_bf16(afh[i], bfl, acc[i][j], 0, 0, 0);
                acc[i][j] = __builtin_amdgcn_mfma_f32_16x16x32_bf16(afl[i], bfh, acc[i][j], 0, 0, 0);
            }
        }
    }

#pragma unroll
    for (int i = 0; i < 4; ++i) {
#pragma unroll
        for (int rg = 0; rg < 4; ++rg) {
            const int gm = m0 + wm * 64 + i * 16 + (ln >> 4) * 4 + rg;
            if (gm >= M) continue;
            const float* addp = ADDROW ? (addrow + (size_t)(gm % addmod) * ldadd) : nullptr;
#pragma unroll
            for (int j = 0; j < 4; ++j) {
                const int gn = n0 + wn * 64 + j * 16 + fr;
                float v = acc[i][j][rg];
                if (BIAS) v += bias[gn];
                if (ADDROW) v += addp[gn];
                if (RELU) v = fmaxf(v, 0.f);
                if (OUTF) Cf[(size_t)z * cbs_ + (size_t)gm * ldc + gn] = v;
                if (OUTS) {
                    const ushort h = f2bf(v);
                    const ushort l = f2bf(v - bf2f(h));
                    ushort* cp = Cs + (size_t)z * csbs_ + (size_t)gm * ldcs;
                    cp[gn] = h;
                    cp[N + gn] = l;
                }
            }
        }
    }
}

// ---------------------------------------------------------------------------
// Gather(optional) + split + zero-pad: row r of src (K cols) -> [r][2*Kpad]
// ---------------------------------------------------------------------------
__global__ void gsplit_k(const float* __restrict__ src, const int* __restrict__ tok,
                         ushort* __restrict__ outp, int K, int Kpad)
{
    const int r = blockIdx.x;
    const float* s = src + (size_t)(tok ? tok[r] : r) * K;
    ushort* o = outp + (size_t)r * 2 * Kpad;
    for (int k = threadIdx.x; k < Kpad; k += blockDim.x) {
        const float x = (k < K) ? s[k] : 0.f;
        const ushort h = f2bf(x);
        const ushort l = f2bf(x - bf2f(h));
        o[k] = h;
        o[Kpad + k] = l;
    }
}

// ---------------------------------------------------------------------------
// fp32 [rows][K] -> split bf16 [rows][2K] (hi | lo)
// ---------------------------------------------------------------------------
__global__ void split_k(const float* __restrict__ in, ushort* __restrict__ outp,
                        int rows, int K)
{
    const int i = blockIdx.x * 256 + threadIdx.x;
    if (i >= rows * K) return;
    const int r = i / K, k = i - r * K;
    const float x = in[i];
    const ushort h = f2bf(x);
    const ushort l = f2bf(x - bf2f(h));
    ushort* o = outp + (size_t)r * 2 * K;
    o[k] = h;
    o[K + k] = l;
}

// ---------------------------------------------------------------------------
// fp32 [R][C] -> split-transposed bf16 [C][2R]
// ---------------------------------------------------------------------------
__global__ __launch_bounds__(256) void tsplit_k(
    const float* __restrict__ in, ushort* __restrict__ outp,
    int R, int C, int ldin, long ibs, long obs)
{
    __shared__ float t[64][65];
    const int c0 = blockIdx.x * 64, r0 = blockIdx.y * 64;
    in   += (size_t)blockIdx.z * ibs;
    outp += (size_t)blockIdx.z * obs;
    const int tx = threadIdx.x & 15, ty = threadIdx.x >> 4;
#pragma unroll
    for (int i = 0; i < 4; ++i) {
        const int r = ty * 4 + i;
        const float4 v = *(const float4*)&in[(size_t)(r0 + r) * ldin + c0 + tx * 4];
        t[tx * 4 + 0][r] = v.x;
        t[tx * 4 + 1][r] = v.y;
        t[tx * 4 + 2][r] = v.z;
        t[tx * 4 + 3][r] = v.w;
    }
    __syncthreads();
    const int R2 = 2 * R;
#pragma unroll
    for (int i = 0; i < 4; ++i) {
        const int c = ty * 4 + i;
        ushort h[4], l[4];
#pragma unroll
        for (int k2 = 0; k2 < 4; ++k2) {
            const float x = t[c][tx * 4 + k2];
            h[k2] = f2bf(x);
            l[k2] = f2bf(x - bf2f(h[k2]));
        }
        uint2 hw, lw;
        hw.x = (unsigned)h[0] | ((unsigned)h[1] << 16);
        hw.y = (unsigned)h[2] | ((unsigned)h[3] << 16);
        lw.x = (unsigned)l[0] | ((unsigned)l[1] << 16);
        lw.y = (unsigned)l[2] | ((unsigned)l[3] << 16);
        *(uint2*)&outp[(size_t)(c0 + c) * R2 + r0 + tx * 4] = hw;
        *(uint2*)&outp[(size_t)(c0 + c) * R2 + R + r0 + tx * 4] = lw;
    }
}

// ---------------------------------------------------------------------------
// Register-resident biLSTM scan v5: atomics-only protocol; act phase all-lane
// redundant via DPP shfl_xor gather (no ds_bpermute broadcasts, no serial
// 1/16-lane act); xg_lds stride-5 layout (conflict-free reads).
// Lane map: lane = ul*16 + ks*4 + gt  (ul=unit-in-wave, ks=k-slice, gt=gate).
// ---------------------------------------------------------------------------
__global__ __launch_bounds__(1024) void lstm_reg_k(
    const float* __restrict__ gxf, const float* __restrict__ gxb,
    const float* __restrict__ whf, const float* __restrict__ whb,
    float* __restrict__ rnn, float* hbuf, int* stamp)
{
    const int p = blockIdx.x;          // pair: batch b=p>>1, dir=p&1
    const int q = blockIdx.y;          // quarter (owns units [64q,64q+64))
    const int b = p >> 1, dir = p & 1;
    const float* xg = dir ? gxb : gxf;
    const float* W  = dir ? whb : whf;
    const int tid = threadIdx.x;
    const int wv = tid >> 6, lane = tid & 63;
    const int ul = lane >> 4;           // unit-local 0..3
    const int ks = (lane >> 2) & 3;     // 64-float k-slice
    const int gt = lane & 3;            // gate 0..3 (i,f,g,o)
    const int u  = wv * 4 + ul;         // block unit 0..63
    const int grow = gt * 256 + q * 64 + u;

    float4 w[16];
    {
        const float4* wp = (const float4*)(W + (size_t)grow * 256 + ks * 64);
#pragma unroll
        for (int i = 0; i < 16; ++i) w[i] = wp[i];
    }

    __shared__ float h_lds[4 * 68];
    __shared__ float xg_lds[320];       // [u*5 + gt], stride 5 = conflict-free

    float* hb0 = hbuf + (size_t)p * 256;            // parity 0
    float* hb1 = hbuf + (size_t)(64 + p) * 256;     // parity 1
    int* sp = stamp + p * 16;

    const size_t xgb = (size_t)b * 256;
    const int g2 = (tid >> 6) * 256 + q * 64 + (tid & 63);  // staging map (tid<256)
    float c = 0.f;                                   // redundant in all lanes
    float xg_cur = 0.f;
    if (tid < 256) xg_cur = xg[(xgb + (dir ? 255 : 0)) * 1024 + g2];

    for (int st = 0; st < 256; ++st) {
        const int ts = dir ? 255 - st : st;
        if (st > 0 && tid == 0) {
            while (true) {
                int s0 = __hip_atomic_load(&sp[0], __ATOMIC_RELAXED, __HIP_MEMORY_SCOPE_AGENT);
                int s1 = __hip_atomic_load(&sp[1], __ATOMIC_RELAXED, __HIP_MEMORY_SCOPE_AGENT);
                int s2 = __hip_atomic_load(&sp[2], __ATOMIC_RELAXED, __HIP_MEMORY_SCOPE_AGENT);
                int s3 = __hip_atomic_load(&sp[3], __ATOMIC_RELAXED, __HIP_MEMORY_SCOPE_AGENT);
                if (min(min(s0, s1), min(s2, s3)) >= st) break;
            }
        }
        __syncthreads();   // B1: partners' h[st-1] published (via atomics)
        if (tid < 256) {
            float hv = 0.f;
            if (st > 0) {
                const float* src = (st & 1) ? hb0 : hb1;   // parity (st-1)&1
                hv = __hip_atomic_load(&src[tid], __ATOMIC_RELAXED, __HIP_MEMORY_SCOPE_AGENT);
            }
            h_lds[(tid >> 6) * 68 + (tid & 63)] = hv;
            xg_lds[(tid & 63) * 5 + (tid >> 6)] = xg_cur;  // [u][gt] stride-5
        }
        __syncthreads();   // B2: h_lds/xg_lds ready
        float acc = 0.f;
        {
            const float4* hp = (const float4*)&h_lds[ks * 68];
#pragma unroll
            for (int i = 0; i < 16; ++i) {
                const float4 hv = hp[i];
                acc = fmaf(w[i].x, hv.x, acc);
                acc = fmaf(w[i].y, hv.y, acc);
                acc = fmaf(w[i].z, hv.z, acc);
                acc = fmaf(w[i].w, hv.w, acc);
            }
        }
        acc += __shfl_xor(acc, 4);      // reduce over ks (bits 2-3): DPP
        acc += __shfl_xor(acc, 8);
        const float g = acc + xg_lds[u * 5 + gt];
        // gather quartet gates via DPP xor-shfls; all lanes act redundantly
        const float t1 = __shfl_xor(g, 1);
        const float t2 = __shfl_xor(g, 2);
        const float t3 = __shfl_xor(t1, 2);
        const float g0 = (gt == 0) ? g : (gt == 1) ? t1 : (gt == 2) ? t2 : t3;
        const float g1 = (gt == 1) ? g : (gt == 0) ? t1 : (gt == 3) ? t2 : t3;
        const float g2v = (gt == 2) ? g : (gt == 3) ? t1 : (gt == 0) ? t2 : t3;
        const float g3v = (gt == 3) ? g : (gt == 2) ? t1 : (gt == 1) ? t2 : t3;
        const float si = 1.f / (1.f + __expf(-g0));
        const float sf = 1.f / (1.f + __expf(-g1));
        const float so = 1.f / (1.f + __expf(-g3v));
        const float tg = 1.f - 2.f / (__expf(2.f * g2v) + 1.f);
        c = sf * c + si * tg;
        const float tc = 1.f - 2.f / (__expf(2.f * c) + 1.f);
        const float hn = so * tc;
        if ((lane & 15) == 0) {          // ks==0 && gt==0: one lane per unit
            float* dst = (st & 1) ? hb1 : hb0;       // parity st&1
            __hip_atomic_store(&dst[q * 64 + u], hn, __ATOMIC_RELAXED, __HIP_MEMORY_SCOPE_AGENT);
            rnn[(xgb + ts) * 512 + (size_t)dir * 256 + q * 64 + u] = hn;
        }
        __syncthreads();   // B3: every wave drains vmcnt(0) -> all h stores acked
        if (tid == 0) {
            __hip_atomic_store(&sp[q], st + 1, __ATOMIC_RELAXED, __HIP_MEMORY_SCOPE_AGENT);
        }
        // prefetch next step's xg (off critical path)
        if (tid < 256 && st < 255) {
            const int tsn = dir ? 254 - st : st + 1;
            xg_cur = xg[(xgb + tsn) * 1024 + g2];
        }
    }
}

__global__ void init_cnt_k(int* stamp) {
    const int i = blockIdx.x * blockDim.x + threadIdx.x;
    if (i < 1024) stamp[i] = 0;
}

// ---------------------------------------------------------------------------
// Masked softmax over s (256); writes split-bf16 probs in place.
// ---------------------------------------------------------------------------
__global__ __launch_bounds__(256) void softmax_split_k(
    float* __restrict__ sc, const int* __restrict__ tokens, int b0)
{
    const int bb = blockIdx.y;
    const int l  = blockIdx.x * 4 + (threadIdx.x >> 6);
    const int lane = threadIdx.x & 63;
    float* row = sc + ((size_t)bb * 4000 + l) * 256;
    const int* tk = tokens + (size_t)(b0 + bb) * 256;
    float4 v = *(const float4*)&row[lane * 4];
    const int4 tv = *(const int4*)&tk[lane * 4];
    if (tv.x == 0) v.x = -1e9f;
    if (tv.y == 0) v.y = -1e9f;
    if (tv.z == 0) v.z = -1e9f;
    if (tv.w == 0) v.w = -1e9f;
    float mx = fmaxf(fmaxf(v.x, v.y), fmaxf(v.z, v.w));
    for (int o = 32; o > 0; o >>= 1) mx = fmaxf(mx, __shfl_xor(mx, o));
    v.x = __expf(v.x - mx); v.y = __expf(v.y - mx);
    v.z = __expf(v.z - mx); v.w = __expf(v.w - mx);
    float s = v.x + v.y + v.z + v.w;
    for (int o = 32; o > 0; o >>= 1) s += __shfl_xor(s, o);
    const float inv = 1.f / s;
    const float p0 = v.x * inv, p1 = v.y * inv, p2 = v.z * inv, p3 = v.w * inv;
    const ushort h0 = f2bf(p0), h1 = f2bf(p1), h2 = f2bf(p2), h3 = f2bf(p3);
    const ushort l0 = f2bf(p0 - bf2f(h0)), l1 = f2bf(p1 - bf2f(h1));
    const ushort l2 = f2bf(p2 - bf2f(h2)), l3 = f2bf(p3 - bf2f(h3));
    ushort* orow = (ushort*)row;
    uint2 hw, lw;
    hw.x = (unsigned)h0 | ((unsigned)h1 << 16);
    hw.y = (unsigned)h2 | ((unsigned)h3 << 16);
    lw.x = (unsigned)l0 | ((unsigned)l1 << 16);
    lw.y = (unsigned)l2 | ((unsigned)l3 << 16);
    *(uint2*)&orow[lane * 4] = hw;
    *(uint2*)&orow[256 + lane * 4] = lw;
}

// ---------------------------------------------------------------------------
// Sparse GCN aggregation.
// ---------------------------------------------------------------------------
__global__ __launch_bounds__(256) void spmm_k(
    const float* __restrict__ adj, const float* __restrict__ tmp,
    const float* __restrict__ bias, float* __restrict__ outp)
{
    const int l = blockIdx.x;
    __shared__ int   idxs[4][256];
    __shared__ float vals[4][256];
    __shared__ int   cnts[4];
    const int t = threadIdx.x;
    const int w = t >> 6, lane = t & 63;
    const float* arow = adj + (size_t)l * 4000;
    int cnt = 0;
    for (int r = 0; r < 16; ++r) {
        const int o = r * 64 + lane;
        const int j = w * 1000 + o;
        const float a = (o < 1000) ? arow[j] : 0.f;
        const unsigned long long mk = __ballot(a != 0.f);
        if (a != 0.f) {
            const int pos = cnt + __popcll(mk & ((1ull << lane) - 1ull));
            if (pos < 256) { idxs[w][pos] = j; vals[w][pos] = a; }
        }
        cnt += __popcll(mk);
    }
    if (lane == 0) cnts[w] = min(cnt, 256);
    __syncthreads();
    const int c0 = t * 2;
    float a0 = 0.f, a1 = 0.f;
    for (int ww = 0; ww < 4; ++ww) {
        const int n = cnts[ww];
        for (int e = 0; e < n; ++e) {
            const float a = vals[ww][e];
            const float2 tv = *(const float2*)&tmp[(size_t)idxs[ww][e] * 512 + c0];
            a0 = fmaf(a, tv.x, a0);
            a1 = fmaf(a, tv.y, a1);
        }
    }
    float2 res;
    res.x = fmaxf(a0 + bias[c0], 0.f);
    res.y = fmaxf(a1 + bias[c0 + 1], 0.f);
    *(float2*)&outp[(size_t)l * 512 + c0] = res;
}

// ---------------------------------------------------------------------------
// Final projection.
// ---------------------------------------------------------------------------
__global__ __launch_bounds__(256) void out_k(
    const float* __restrict__ x2, const float* __restrict__ w_out,
    const float* __restrict__ b_out, float* __restrict__ outp, int b0)
{
    const int r = blockIdx.x * 4 + (threadIdx.x >> 6);
    const int lane = threadIdx.x & 63;
    const float4 xv = *(const float4*)&x2[(size_t)r * 256 + lane * 4];
    const float4 wv = *(const float4*)&w_out[lane * 4];
    float s = xv.x * wv.x + xv.y * wv.y + xv.z * wv.z + xv.w * wv.w;
    for (int o = 32; o > 0; o >>= 1) s += __shfl_xor(s, o);
    if (lane == 0) {
        const int bb = r / 4000, l = r - bb * 4000;
        outp[(size_t)(b0 + bb) * 4000 + l] = s + b_out[0];
    }
}

// ---------------------------------------------------------------------------
extern "C" void kernel_launch(void* const* d_in, const int* in_sizes, int n_in,
                              void* d_out, int out_size, void* d_ws, size_t ws_size,
                              hipStream_t stream)
{
    const int*   tokens    = (const int*)  d_in[0];
    const float* emb       = (const float*)d_in[1];
    const float* w_ih_f    = (const float*)d_in[2];
    const float* w_hh_f    = (const float*)d_in[3];
    const float* b_f       = (const float*)d_in[4];
    const float* w_ih_b    = (const float*)d_in[5];
    const float* w_hh_b    = (const float*)d_in[6];
    const float* b_b       = (const float*)d_in[7];
    const float* attn_w    = (const float*)d_in[8];
    const float* label_emb = (const float*)d_in[9];
    const float* adj       = (const float*)d_in[10];
    const float* gcn_w     = (const float*)d_in[11];
    const float* gcn_b     = (const float*)d_in[12];
    const float* w1        = (const float*)d_in[13];
    const float* b1        = (const float*)d_in[14];
    const float* w2        = (const float*)d_in[15];
    const float* b2        = (const float*)d_in[16];
    const float* w_out     = (const float*)d_in[17];
    const float* b_out     = (const float*)d_in[18];
    float* outp = (float*)d_out;
    float* wsf  = (float*)d_ws;

    // ---- workspace layout (float offsets) ----
    const size_t off_gf  = 0;          // gates_f 8.39M
    const size_t off_gb  = 8388608;    // gates_b 8.39M
    const size_t off_rnn = 16777216;   // rnn fp32 4.19M
    const size_t off_tmp = 20971520;   // gcn_tmp 2.05M (lstm hbuf/stamp overlay)
    const size_t off_go  = 23019520;   // gcn_out 2.05M
    const size_t off_ctr = 25067520;   // contrib 2.05M
    const size_t base_end = 27115520;
    const size_t S_sz = 10829824;
    const size_t have = ws_size / 4;
    int NB = 1; size_t offS = off_gf, offC = off_gf + S_sz;
    {
        const int tiers[6] = {32, 16, 8, 4, 2, 0};
        bool found = false;
        for (int t = 0; tiers[t]; ++t) {
            if (have >= base_end + S_sz + (size_t)tiers[t] * 5120000) {
                NB = tiers[t]; offS = base_end; offC = base_end + S_sz; found = true; break;
            }
        }
        if (!found && have >= base_end + S_sz) { NB = 2; offS = base_end; offC = off_gf; }
    }

    float* gates_f = wsf + off_gf;
    float* gates_b = wsf + off_gb;
    float* rnn     = wsf + off_rnn;
    float* gcn_tmp = wsf + off_tmp;
    float* gcn_out = wsf + off_go;
    float* contrib = wsf + off_ctr;
    float* hbuf    = wsf + off_tmp;                  // [2][64][256] overlay
    int*   stamp   = (int*)(wsf + off_tmp + 32768);  // [64][16] overlay

    // pre-lstm split staging (dead before its host region is reused)
    const size_t off_esp = (offS == off_gf) ? off_rnn : offS;
    ushort* esplit  = (ushort*)(wsf + off_esp);
    ushort* wsplitf = esplit + (size_t)8192 * 640;
    ushort* wsplitb = wsplitf + (size_t)1024 * 640;

    ushort* attn_ws16 = (ushort*)(wsf + offS);                // [4000][1024]
    ushort* w1t16     = (ushort*)(wsf + offS + 2048000);      // [512][1024]
    ushort* w2t16     = (ushort*)(wsf + offS + 2310144);      // [256][1024]
    ushort* rnn_nt16  = (ushort*)(wsf + offS + 2441216);      // [32][256][1024]
    ushort* rnnT16    = (ushort*)(wsf + offS + 6635520);      // [32][512][512]

    float*  scoresb = wsf + offC;
    ushort* attn16  = (ushort*)(wsf + offC + (size_t)NB * 1024000);
    ushort* x116    = (ushort*)(wsf + offC + (size_t)NB * 1024000 + (size_t)NB * 2048000);
    float*  x2b     = scoresb;

    // 0. zero lstm stamps
    init_cnt_k<<<4, 256, 0, stream>>>(stamp);

    // 1. input projections on MFMA
    gsplit_k<<<8192, 256, 0, stream>>>(emb, tokens, esplit, 300, 320);
    gsplit_k<<<1024, 256, 0, stream>>>(w_ih_f, nullptr, wsplitf, 300, 320);
    gsplit_k<<<1024, 256, 0, stream>>>(w_ih_b, nullptr, wsplitb, 300, 320);
    mgemm_k<true, false, false, true, false><<<dim3(64, 8, 1), 256, 0, stream>>>(
        esplit, wsplitf, gates_f, nullptr,
        8192, 1024, 320, 640, 640, 1024, 0,
        0L, 0L, 0L, 0L, b_f, nullptr, 1, 0);
    mgemm_k<true, false, false, true, false><<<dim3(64, 8, 1), 256, 0, stream>>>(
        esplit, wsplitb, gates_b, nullptr,
        8192, 1024, 320, 640, 640, 1024, 0,
        0L, 0L, 0L, 0L, b_b, nullptr, 1, 0);

    // 2. biLSTM scan -> rnn [B,S,512]
    lstm_reg_k<<<dim3(64, 4), 1024, 0, stream>>>(
        gates_f, gates_b, w_hh_f, w_hh_b, rnn, hbuf, stamp);

    // 3. split conversions for the head
    split_k<<<16384, 256, 0, stream>>>(rnn, rnn_nt16, 8192, 512);
    tsplit_k<<<dim3(8, 4, 32), 256, 0, stream>>>(rnn, rnnT16, 256, 512, 512, 131072, 262144);
    split_k<<<8000, 256, 0, stream>>>(attn_w, attn_ws16, 4000, 512);
    tsplit_k<<<dim3(8, 8, 1), 256, 0, stream>>>(w1, w1t16, 512, 512, 512, 0, 0);
    tsplit_k<<<dim3(4, 8, 1), 256, 0, stream>>>(w2, w2t16, 512, 256, 256, 0, 0);

    // 4. GCN branch
    gemm_k<false, false><<<dim3(4, 63, 1), 256, 0, stream>>>(
        label_emb, gcn_w, gcn_tmp, 4000, 512, 256, 256, 512, 512,
        0, 0, 0, nullptr, nullptr, nullptr, 1, 0, 0);
    spmm_k<<<dim3(4000), 256, 0, stream>>>(adj, gcn_tmp, gcn_b, gcn_out);
    gemm_k<false, false><<<dim3(4, 63, 1), 256, 0, stream>>>(
        gcn_out, w1 + (size_t)512 * 512, contrib, 4000, 512, 512, 512, 512, 512,
        0, 0, 0, nullptr, b1, nullptr, 1, 0, 0);

    // 5. attention + MLP head (MFMA split-bf16), chunked over batch
    for (int b0 = 0; b0 < 32; b0 += NB) {
        const int nb = (32 - b0 < NB) ? (32 - b0) : NB;
        mgemm_k<false, false, false, true, false><<<dim3(32, 2, nb), 256, 0, stream>>>(
            attn_ws16, rnn_nt16 + (size_t)b0 * 262144, scoresb, nullptr,
            4000, 256, 512, 1024, 1024, 256, 0,
            0L, 262144L, 1024000L, 0L, nullptr, nullptr, 1, 0);
        softmax_split_k<<<dim3(1000, nb), 256, 0, stream>>>(scoresb, tokens, b0);
        mgemm_k<false, false, false, false, true><<<dim3(32, 4, nb), 256, 0, stream>>>(
            (const ushort*)scoresb, rnnT16 + (size_t)b0 * 262144, nullptr, attn16,
            4000, 512, 256, 512, 512, 0, 1024,
            2048000L, 262144L, 0L, 4096000L, nullptr, nullptr, 1, 0);
        mgemm_k<false, true, true, false, true><<<dim3((nb * 4000 + 127) / 128, 4, 1), 256, 0, stream>>>(
            attn16, w1t16, nullptr, x116,
            nb * 4000, 512, 512, 1024, 1024, 0, 1024,
            0L, 0L, 0L, 0L, nullptr, contrib, 4000, 512);
        mgemm_k<true, false, true, true, false><<<dim3((nb * 4000 + 127) / 128, 2, 1), 256, 0, stream>>>(
            x116, w2t16, x2b, nullptr,
            nb * 4000, 256, 512, 1024, 1024, 256, 0,
            0L, 0L, 0L, 0L, b2, nullptr, 1, 0);
        out_k<<<dim3(nb * 1000), 256, 0, stream>>>(x2b, w_out, b_out, outp, b0);
    }
}

// Round 8
// 1745.102 us; speedup vs baseline: 4.0111x; 1.1271x over previous
//
#include <hip/hip_runtime.h>
#include <hip/hip_bf16.h>
#include <math.h>

// Problem constants
// B=32 S=256 E=300 H=256(4H=1024) L=4000 D=256 G=512 V=50000 LIN1=512 LIN2=256, 2H=512

typedef __attribute__((ext_vector_type(8))) short bfrag;   // 8 bf16 (4 VGPRs)
typedef __attribute__((ext_vector_type(4))) float ffrag;   // 4 fp32 acc

__device__ __forceinline__ ushort f2bf(float x) {
    union { float f; unsigned u; } c; c.f = x;
    const unsigned r = c.u + 0x7fffu + ((c.u >> 16) & 1u);
    return (ushort)(r >> 16);
}
__device__ __forceinline__ float bf2f(ushort h) {
    union { unsigned u; float f; } c; c.u = (unsigned)h << 16;
    return c.f;
}

// ---------------------------------------------------------------------------
// Split-bf16 MFMA GEMM: C = A * B^T via 3-term split (hh + hl + lh).
// A: [M][lda] bf16, row = [hi(0..K) | lo(0..K)]; B likewise. Tile 128x128,
// BK=32, 4 waves (2x2 of 64x64). LDS rows padded to 40 bf16 (80B stride).
// Pipeline: next-tile loads issued before the MFMA phase (latency hides).
// ---------------------------------------------------------------------------
template<bool BIAS, bool ADDROW, bool RELU, bool OUTF, bool OUTS>
__global__ __launch_bounds__(256) void mgemm_k(
    const ushort* __restrict__ A, const ushort* __restrict__ B,
    float* __restrict__ Cf, ushort* __restrict__ Cs,
    int M, int N, int K, int lda, int ldb, int ldc, int ldcs,
    long abs_, long bbs_, long cbs_, long csbs_,
    const float* __restrict__ bias,
    const float* __restrict__ addrow, int addmod, int ldadd)
{
    const int tid = threadIdx.x;
    const int ln = tid & 63;
    const int wv = tid >> 6;
    const int wm = wv >> 1, wn = wv & 1;
    const int m0 = blockIdx.x * 128, n0 = blockIdx.y * 128;
    const int z = blockIdx.z;
    A += (size_t)z * abs_;
    B += (size_t)z * bbs_;

    __shared__ ushort Ah[128 * 40], Al[128 * 40], Bh[128 * 40], Bl[128 * 40];

    ffrag acc[4][4];
#pragma unroll
    for (int i = 0; i < 4; ++i)
#pragma unroll
        for (int j = 0; j < 4; ++j) acc[i][j] = ffrag{0.f, 0.f, 0.f, 0.f};

    const int sr = tid >> 1;
    const int sk = (tid & 1) * 16;
    const int am = min(m0 + sr, M - 1);
    const int bn = n0 + sr;
    const int fr = ln & 15;
    const int fk = (ln >> 4) * 8;

    const ushort* arow = A + (size_t)am * lda + sk;
    const ushort* brow = B + (size_t)bn * ldb + sk;

    bfrag ah0, ah1, al0, al1, bh0, bh1, bl0, bl1;
    {
        const ushort* ap = arow;
        const ushort* bp = brow;
        ah0 = *(const bfrag*)ap;       ah1 = *(const bfrag*)(ap + 8);
        al0 = *(const bfrag*)(ap + K); al1 = *(const bfrag*)(ap + K + 8);
        bh0 = *(const bfrag*)bp;       bh1 = *(const bfrag*)(bp + 8);
        bl0 = *(const bfrag*)(bp + K); bl1 = *(const bfrag*)(bp + K + 8);
    }

    for (int k0 = 0; k0 < K; k0 += 32) {
        __syncthreads();   // previous iteration's frag reads complete
        *(bfrag*)&Ah[sr * 40 + sk] = ah0;  *(bfrag*)&Ah[sr * 40 + sk + 8] = ah1;
        *(bfrag*)&Al[sr * 40 + sk] = al0;  *(bfrag*)&Al[sr * 40 + sk + 8] = al1;
        *(bfrag*)&Bh[sr * 40 + sk] = bh0;  *(bfrag*)&Bh[sr * 40 + sk + 8] = bh1;
        *(bfrag*)&Bl[sr * 40 + sk] = bl0;  *(bfrag*)&Bl[sr * 40 + sk + 8] = bl1;
        __syncthreads();   // tile staged
        if (k0 + 32 < K) {  // issue next-tile loads early
            const ushort* ap = arow + k0 + 32;
            const ushort* bp = brow + k0 + 32;
            ah0 = *(const bfrag*)ap;       ah1 = *(const bfrag*)(ap + 8);
            al0 = *(const bfrag*)(ap + K); al1 = *(const bfrag*)(ap + K + 8);
            bh0 = *(const bfrag*)bp;       bh1 = *(const bfrag*)(bp + 8);
            bl0 = *(const bfrag*)(bp + K); bl1 = *(const bfrag*)(bp + K + 8);
        }
        bfrag afh[4], afl[4];
#pragma unroll
        for (int i = 0; i < 4; ++i) {
            const int ar = (wm * 64 + i * 16 + fr) * 40 + fk;
            afh[i] = *(const bfrag*)&Ah[ar];
            afl[i] = *(const bfrag*)&Al[ar];
        }
#pragma unroll
        for (int j = 0; j < 4; ++j) {
            const int br = (wn * 64 + j * 16 + fr) * 40 + fk;
            const bfrag bfh = *(const bfrag*)&Bh[br];
            const bfrag bfl = *(const bfrag*)&Bl[br];
#pragma unroll
            for (int i = 0; i < 4; ++i) {
                acc[i][j] = __builtin_amdgcn_mfma_f32_16x16x32_bf16(afh[i], bfh, acc[i][j], 0, 0, 0);
                acc[i][j] = __builtin_amdgcn_mfma_f32_16x16x32_bf16(afh[i], bfl, acc[i][j], 0, 0, 0);
                acc[i][j] = __builtin_amdgcn_mfma_f32_16x16x32_bf16(afl[i], bfh, acc[i][j], 0, 0, 0);
            }
        }
    }

#pragma unroll
    for (int i = 0; i < 4; ++i) {
#pragma unroll
        for (int rg = 0; rg < 4; ++rg) {
            const int gm = m0 + wm * 64 + i * 16 + (ln >> 4) * 4 + rg;
            if (gm >= M) continue;
            const float* addp = ADDROW ? (addrow + (size_t)(gm % addmod) * ldadd) : nullptr;
#pragma unroll
            for (int j = 0; j < 4; ++j) {
                const int gn = n0 + wn * 64 + j * 16 + fr;
                float v = acc[i][j][rg];
                if (BIAS) v += bias[gn];
                if (ADDROW) v += addp[gn];
                if (RELU) v = fmaxf(v, 0.f);
                if (OUTF) Cf[(size_t)z * cbs_ + (size_t)gm * ldc + gn] = v;
                if (OUTS) {
                    const ushort h = f2bf(v);
                    const ushort l = f2bf(v - bf2f(h));
                    ushort* cp = Cs + (size_t)z * csbs_ + (size_t)gm * ldcs;
                    cp[gn] = h;
                    cp[N + gn] = l;
                }
            }
        }
    }
}

// ---------------------------------------------------------------------------
// Gather(optional) + split + zero-pad: row r of src (K cols) -> [r][2*Kpad]
// ---------------------------------------------------------------------------
__global__ void gsplit_k(const float* __restrict__ src, const int* __restrict__ tok,
                         ushort* __restrict__ outp, int K, int Kpad)
{
    const int r = blockIdx.x;
    const float* s = src + (size_t)(tok ? tok[r] : r) * K;
    ushort* o = outp + (size_t)r * 2 * Kpad;
    for (int k = threadIdx.x; k < Kpad; k += blockDim.x) {
        const float x = (k < K) ? s[k] : 0.f;
        const ushort h = f2bf(x);
        const ushort l = f2bf(x - bf2f(h));
        o[k] = h;
        o[Kpad + k] = l;
    }
}

// ---------------------------------------------------------------------------
// fp32 [rows][K] -> split bf16 [rows][2K] (hi | lo)
// ---------------------------------------------------------------------------
__global__ void split_k(const float* __restrict__ in, ushort* __restrict__ outp,
                        int rows, int K)
{
    const int i = blockIdx.x * 256 + threadIdx.x;
    if (i >= rows * K) return;
    const int r = i / K, k = i - r * K;
    const float x = in[i];
    const ushort h = f2bf(x);
    const ushort l = f2bf(x - bf2f(h));
    ushort* o = outp + (size_t)r * 2 * K;
    o[k] = h;
    o[K + k] = l;
}

// ---------------------------------------------------------------------------
// fp32 [R][C] -> split-transposed bf16 [C][2R]
// ---------------------------------------------------------------------------
__global__ __launch_bounds__(256) void tsplit_k(
    const float* __restrict__ in, ushort* __restrict__ outp,
    int R, int C, int ldin, long ibs, long obs)
{
    __shared__ float t[64][65];
    const int c0 = blockIdx.x * 64, r0 = blockIdx.y * 64;
    in   += (size_t)blockIdx.z * ibs;
    outp += (size_t)blockIdx.z * obs;
    const int tx = threadIdx.x & 15, ty = threadIdx.x >> 4;
#pragma unroll
    for (int i = 0; i < 4; ++i) {
        const int r = ty * 4 + i;
        const float4 v = *(const float4*)&in[(size_t)(r0 + r) * ldin + c0 + tx * 4];
        t[tx * 4 + 0][r] = v.x;
        t[tx * 4 + 1][r] = v.y;
        t[tx * 4 + 2][r] = v.z;
        t[tx * 4 + 3][r] = v.w;
    }
    __syncthreads();
    const int R2 = 2 * R;
#pragma unroll
    for (int i = 0; i < 4; ++i) {
        const int c = ty * 4 + i;
        ushort h[4], l[4];
#pragma unroll
        for (int k2 = 0; k2 < 4; ++k2) {
            const float x = t[c][tx * 4 + k2];
            h[k2] = f2bf(x);
            l[k2] = f2bf(x - bf2f(h[k2]));
        }
        uint2 hw, lw;
        hw.x = (unsigned)h[0] | ((unsigned)h[1] << 16);
        hw.y = (unsigned)h[2] | ((unsigned)h[3] << 16);
        lw.x = (unsigned)l[0] | ((unsigned)l[1] << 16);
        lw.y = (unsigned)l[2] | ((unsigned)l[3] << 16);
        *(uint2*)&outp[(size_t)(c0 + c) * R2 + r0 + tx * 4] = hw;
        *(uint2*)&outp[(size_t)(c0 + c) * R2 + R + r0 + tx * 4] = lw;
    }
}

// ---------------------------------------------------------------------------
// Register-resident biLSTM scan v6: TAGGED-H protocol. Each h word is a
// 64-bit atomic (hi32 = step tag, lo32 = fp32 h). Readers spin directly on
// the tagged words -> no stamp array, no poll phase, no release drain.
// Parity double-buffer + exact tag check; skew bounded to 1 step by the
// transitive read-before-overwrite chain. 2 barriers/step.
// Co-residency: 256 blocks <= 256 CUs (1 block/CU) => no deadlock.
// ---------------------------------------------------------------------------
__global__ __launch_bounds__(1024) void lstm_reg_k(
    const float* __restrict__ gxf, const float* __restrict__ gxb,
    const float* __restrict__ whf, const float* __restrict__ whb,
    float* __restrict__ rnn, unsigned long long* hbuf)
{
    const int p = blockIdx.x;          // pair: batch b=p>>1, dir=p&1
    const int q = blockIdx.y;          // quarter (owns units [64q,64q+64))
    const int b = p >> 1, dir = p & 1;
    const float* xg = dir ? gxb : gxf;
    const float* W  = dir ? whb : whf;
    const int tid = threadIdx.x;
    const int wv = tid >> 6, lane = tid & 63;
    const int ul = lane >> 4;           // unit-local 0..3
    const int ks = (lane >> 2) & 3;     // 64-float k-slice
    const int gt = lane & 3;            // gate 0..3 (i,f,g,o)
    const int u  = wv * 4 + ul;         // block unit 0..63
    const int grow = gt * 256 + q * 64 + u;

    float4 w[16];
    {
        const float4* wp = (const float4*)(W + (size_t)grow * 256 + ks * 64);
#pragma unroll
        for (int i = 0; i < 16; ++i) w[i] = wp[i];
    }

    __shared__ float h_lds[4 * 68];
    __shared__ float xg_lds[320];       // [u*5 + gt], stride 5 = conflict-free

    unsigned long long* hb0 = hbuf + (size_t)p * 256;            // parity 0
    unsigned long long* hb1 = hbuf + (size_t)(64 + p) * 256;     // parity 1

    const size_t xgb = (size_t)b * 256;
    const int g2 = (tid >> 6) * 256 + q * 64 + (tid & 63);  // staging map (tid<256)
    float c = 0.f;                                   // redundant in all lanes
    float xg_cur = 0.f;
    if (tid < 256) xg_cur = xg[(xgb + (dir ? 255 : 0)) * 1024 + g2];

    for (int st = 0; st < 256; ++st) {
        const int ts = dir ? 255 - st : st;
        if (tid < 256) {
            float hv = 0.f;
            if (st > 0) {
                unsigned long long* src = (st & 1) ? hb0 : hb1;  // parity (st-1)&1
                unsigned long long wd;
                do {
                    wd = __hip_atomic_load(&src[tid], __ATOMIC_RELAXED, __HIP_MEMORY_SCOPE_AGENT);
                } while ((unsigned)(wd >> 32) != (unsigned)st);
                union { unsigned uu; float f; } cv; cv.uu = (unsigned)wd;
                hv = cv.f;
            }
            h_lds[(tid >> 6) * 68 + (tid & 63)] = hv;
            xg_lds[(tid & 63) * 5 + (tid >> 6)] = xg_cur;  // [u][gt] stride-5
        }
        __syncthreads();   // B1: h_lds/xg_lds ready
        float acc = 0.f;
        {
            const float4* hp = (const float4*)&h_lds[ks * 68];
#pragma unroll
            for (int i = 0; i < 16; ++i) {
                const float4 hv = hp[i];
                acc = fmaf(w[i].x, hv.x, acc);
                acc = fmaf(w[i].y, hv.y, acc);
                acc = fmaf(w[i].z, hv.z, acc);
                acc = fmaf(w[i].w, hv.w, acc);
            }
        }
        acc += __shfl_xor(acc, 4);      // reduce over ks (bits 2-3)
        acc += __shfl_xor(acc, 8);
        const float g = acc + xg_lds[u * 5 + gt];
        __syncthreads();   // B2: all LDS reads done -> next stage may overwrite
        // gather quartet gates via xor-shfls; all lanes act redundantly (regs only)
        const float t1 = __shfl_xor(g, 1);
        const float t2 = __shfl_xor(g, 2);
        const float t3 = __shfl_xor(t1, 2);
        const float g0 = (gt == 0) ? g : (gt == 1) ? t1 : (gt == 2) ? t2 : t3;
        const float g1 = (gt == 1) ? g : (gt == 0) ? t1 : (gt == 3) ? t2 : t3;
        const float g2v = (gt == 2) ? g : (gt == 3) ? t1 : (gt == 0) ? t2 : t3;
        const float g3v = (gt == 3) ? g : (gt == 2) ? t1 : (gt == 1) ? t2 : t3;
        const float si = 1.f / (1.f + __expf(-g0));
        const float sf = 1.f / (1.f + __expf(-g1));
        const float so = 1.f / (1.f + __expf(-g3v));
        const float tg = 1.f - 2.f / (__expf(2.f * g2v) + 1.f);
        c = sf * c + si * tg;
        const float tc = 1.f - 2.f / (__expf(2.f * c) + 1.f);
        const float hn = so * tc;
        if ((lane & 15) == 0) {          // ks==0 && gt==0: one lane per unit
            unsigned long long* dst = (st & 1) ? hb1 : hb0;       // parity st&1
            union { float f; unsigned uu; } hv2; hv2.f = hn;
            const unsigned long long wd =
                ((unsigned long long)(unsigned)(st + 1) << 32) | (unsigned long long)hv2.uu;
            __hip_atomic_store(&dst[q * 64 + u], wd, __ATOMIC_RELAXED, __HIP_MEMORY_SCOPE_AGENT);
            rnn[(xgb + ts) * 512 + (size_t)dir * 256 + q * 64 + u] = hn;
        }
        // prefetch next step's xg (off critical path)
        if (tid < 256 && st < 255) {
            const int tsn = dir ? 254 - st : st + 1;
            xg_cur = xg[(xgb + tsn) * 1024 + g2];
        }
    }
}

__global__ void init_hbuf_k(unsigned long long* hbuf) {
    const int i = blockIdx.x * 256 + threadIdx.x;
    if (i < 32768) hbuf[i] = 0ull;
}

// ---------------------------------------------------------------------------
// Masked softmax over s (256); writes split-bf16 probs in place.
// ---------------------------------------------------------------------------
__global__ __launch_bounds__(256) void softmax_split_k(
    float* __restrict__ sc, const int* __restrict__ tokens, int b0)
{
    const int bb = blockIdx.y;
    const int l  = blockIdx.x * 4 + (threadIdx.x >> 6);
    const int lane = threadIdx.x & 63;
    float* row = sc + ((size_t)bb * 4000 + l) * 256;
    const int* tk = tokens + (size_t)(b0 + bb) * 256;
    float4 v = *(const float4*)&row[lane * 4];
    const int4 tv = *(const int4*)&tk[lane * 4];
    if (tv.x == 0) v.x = -1e9f;
    if (tv.y == 0) v.y = -1e9f;
    if (tv.z == 0) v.z = -1e9f;
    if (tv.w == 0) v.w = -1e9f;
    float mx = fmaxf(fmaxf(v.x, v.y), fmaxf(v.z, v.w));
    for (int o = 32; o > 0; o >>= 1) mx = fmaxf(mx, __shfl_xor(mx, o));
    v.x = __expf(v.x - mx); v.y = __expf(v.y - mx);
    v.z = __expf(v.z - mx); v.w = __expf(v.w - mx);
    float s = v.x + v.y + v.z + v.w;
    for (int o = 32; o > 0; o >>= 1) s += __shfl_xor(s, o);
    const float inv = 1.f / s;
    const float p0 = v.x * inv, p1 = v.y * inv, p2 = v.z * inv, p3 = v.w * inv;
    const ushort h0 = f2bf(p0), h1 = f2bf(p1), h2 = f2bf(p2), h3 = f2bf(p3);
    const ushort l0 = f2bf(p0 - bf2f(h0)), l1 = f2bf(p1 - bf2f(h1));
    const ushort l2 = f2bf(p2 - bf2f(h2)), l3 = f2bf(p3 - bf2f(h3));
    ushort* orow = (ushort*)row;
    uint2 hw, lw;
    hw.x = (unsigned)h0 | ((unsigned)h1 << 16);
    hw.y = (unsigned)h2 | ((unsigned)h3 << 16);
    lw.x = (unsigned)l0 | ((unsigned)l1 << 16);
    lw.y = (unsigned)l2 | ((unsigned)l3 << 16);
    *(uint2*)&orow[lane * 4] = hw;
    *(uint2*)&orow[256 + lane * 4] = lw;
}

// ---------------------------------------------------------------------------
// Sparse GCN aggregation.
// ---------------------------------------------------------------------------
__global__ __launch_bounds__(256) void spmm_k(
    const float* __restrict__ adj, const float* __restrict__ tmp,
    const float* __restrict__ bias, float* __restrict__ outp)
{
    const int l = blockIdx.x;
    __shared__ int   idxs[4][256];
    __shared__ float vals[4][256];
    __shared__ int   cnts[4];
    const int t = threadIdx.x;
    const int w = t >> 6, lane = t & 63;
    const float* arow = adj + (size_t)l * 4000;
    int cnt = 0;
    for (int r = 0; r < 16; ++r) {
        const int o = r * 64 + lane;
        const int j = w * 1000 + o;
        const float a = (o < 1000) ? arow[j] : 0.f;
        const unsigned long long mk = __ballot(a != 0.f);
        if (a != 0.f) {
            const int pos = cnt + __popcll(mk & ((1ull << lane) - 1ull));
            if (pos < 256) { idxs[w][pos] = j; vals[w][pos] = a; }
        }
        cnt += __popcll(mk);
    }
    if (lane == 0) cnts[w] = min(cnt, 256);
    __syncthreads();
    const int c0 = t * 2;
    float a0 = 0.f, a1 = 0.f;
    for (int ww = 0; ww < 4; ++ww) {
        const int n = cnts[ww];
        for (int e = 0; e < n; ++e) {
            const float a = vals[ww][e];
            const float2 tv = *(const float2*)&tmp[(size_t)idxs[ww][e] * 512 + c0];
            a0 = fmaf(a, tv.x, a0);
            a1 = fmaf(a, tv.y, a1);
        }
    }
    float2 res;
    res.x = fmaxf(a0 + bias[c0], 0.f);
    res.y = fmaxf(a1 + bias[c0 + 1], 0.f);
    *(float2*)&outp[(size_t)l * 512 + c0] = res;
}

// ---------------------------------------------------------------------------
// Final projection.
// ---------------------------------------------------------------------------
__global__ __launch_bounds__(256) void out_k(
    const float* __restrict__ x2, const float* __restrict__ w_out,
    const float* __restrict__ b_out, float* __restrict__ outp, int b0)
{
    const int r = blockIdx.x * 4 + (threadIdx.x >> 6);
    const int lane = threadIdx.x & 63;
    const float4 xv = *(const float4*)&x2[(size_t)r * 256 + lane * 4];
    const float4 wv = *(const float4*)&w_out[lane * 4];
    float s = xv.x * wv.x + xv.y * wv.y + xv.z * wv.z + xv.w * wv.w;
    for (int o = 32; o > 0; o >>= 1) s += __shfl_xor(s, o);
    if (lane == 0) {
        const int bb = r / 4000, l = r - bb * 4000;
        outp[(size_t)(b0 + bb) * 4000 + l] = s + b_out[0];
    }
}

// ---------------------------------------------------------------------------
extern "C" void kernel_launch(void* const* d_in, const int* in_sizes, int n_in,
                              void* d_out, int out_size, void* d_ws, size_t ws_size,
                              hipStream_t stream)
{
    const int*   tokens    = (const int*)  d_in[0];
    const float* emb       = (const float*)d_in[1];
    const float* w_ih_f    = (const float*)d_in[2];
    const float* w_hh_f    = (const float*)d_in[3];
    const float* b_f       = (const float*)d_in[4];
    const float* w_ih_b    = (const float*)d_in[5];
    const float* w_hh_b    = (const float*)d_in[6];
    const float* b_b       = (const float*)d_in[7];
    const float* attn_w    = (const float*)d_in[8];
    const float* label_emb = (const float*)d_in[9];
    const float* adj       = (const float*)d_in[10];
    const float* gcn_w     = (const float*)d_in[11];
    const float* gcn_b     = (const float*)d_in[12];
    const float* w1        = (const float*)d_in[13];
    const float* b1        = (const float*)d_in[14];
    const float* w2        = (const float*)d_in[15];
    const float* b2        = (const float*)d_in[16];
    const float* w_out     = (const float*)d_in[17];
    const float* b_out     = (const float*)d_in[18];
    float* outp = (float*)d_out;
    float* wsf  = (float*)d_ws;

    // ---- workspace layout (float offsets) ----
    const size_t off_gf  = 0;          // gates_f 8.39M
    const size_t off_gb  = 8388608;    // gates_b 8.39M
    const size_t off_rnn = 16777216;   // rnn fp32 4.19M
    const size_t off_tmp = 20971520;   // gcn_tmp 2.05M (lstm hbuf overlay, 8B-aligned)
    const size_t off_go  = 23019520;   // gcn_out 2.05M
    const size_t off_ctr = 25067520;   // contrib 2.05M
    const size_t base_end = 27115520;
    const size_t S_sz = 10829824;
    const size_t have = ws_size / 4;
    int NB = 1; size_t offS = off_gf, offC = off_gf + S_sz;
    {
        const int tiers[6] = {32, 16, 8, 4, 2, 0};
        bool found = false;
        for (int t = 0; tiers[t]; ++t) {
            if (have >= base_end + S_sz + (size_t)tiers[t] * 5120000) {
                NB = tiers[t]; offS = base_end; offC = base_end + S_sz; found = true; break;
            }
        }
        if (!found && have >= base_end + S_sz) { NB = 2; offS = base_end; offC = off_gf; }
    }

    float* gates_f = wsf + off_gf;
    float* gates_b = wsf + off_gb;
    float* rnn     = wsf + off_rnn;
    float* gcn_tmp = wsf + off_tmp;
    float* gcn_out = wsf + off_go;
    float* contrib = wsf + off_ctr;
    unsigned long long* hbuf = (unsigned long long*)(wsf + off_tmp);  // [2][64][256] u64 overlay

    // pre-lstm split staging (dead before its host region is reused)
    const size_t off_esp = (offS == off_gf) ? off_rnn : offS;
    ushort* esplit  = (ushort*)(wsf + off_esp);
    ushort* wsplitf = esplit + (size_t)8192 * 640;
    ushort* wsplitb = wsplitf + (size_t)1024 * 640;

    ushort* attn_ws16 = (ushort*)(wsf + offS);                // [4000][1024]
    ushort* w1t16     = (ushort*)(wsf + offS + 2048000);      // [512][1024]
    ushort* w2t16     = (ushort*)(wsf + offS + 2310144);      // [256][1024]
    ushort* rnn_nt16  = (ushort*)(wsf + offS + 2441216);      // [32][256][1024]
    ushort* rnnT16    = (ushort*)(wsf + offS + 6635520);      // [32][512][512]

    float*  scoresb = wsf + offC;
    ushort* attn16  = (ushort*)(wsf + offC + (size_t)NB * 1024000);
    ushort* x116    = (ushort*)(wsf + offC + (size_t)NB * 1024000 + (size_t)NB * 2048000);
    float*  x2b     = scoresb;

    // GCN split staging, overlays the chunk region (dead before head loop)
    ushort* le16   = (ushort*)(wsf + offC);                   // [4000][512]
    ushort* gw16   = le16 + (size_t)4000 * 512;               // [512][512]
    ushort* go16   = gw16 + (size_t)512 * 512;                // [4000][1024]
    ushort* w1b16  = go16 + (size_t)4000 * 1024;              // [512][1024]

    // 0. zero tagged-h buffer (graph-replay safe)
    init_hbuf_k<<<128, 256, 0, stream>>>(hbuf);

    // 1. input projections on MFMA
    gsplit_k<<<8192, 256, 0, stream>>>(emb, tokens, esplit, 300, 320);
    gsplit_k<<<1024, 256, 0, stream>>>(w_ih_f, nullptr, wsplitf, 300, 320);
    gsplit_k<<<1024, 256, 0, stream>>>(w_ih_b, nullptr, wsplitb, 300, 320);
    mgemm_k<true, false, false, true, false><<<dim3(64, 8, 1), 256, 0, stream>>>(
        esplit, wsplitf, gates_f, nullptr,
        8192, 1024, 320, 640, 640, 1024, 0,
        0L, 0L, 0L, 0L, b_f, nullptr, 1, 0);
    mgemm_k<true, false, false, true, false><<<dim3(64, 8, 1), 256, 0, stream>>>(
        esplit, wsplitb, gates_b, nullptr,
        8192, 1024, 320, 640, 640, 1024, 0,
        0L, 0L, 0L, 0L, b_b, nullptr, 1, 0);

    // 2. biLSTM scan -> rnn [B,S,512] (tagged-h protocol)
    lstm_reg_k<<<dim3(64, 4), 1024, 0, stream>>>(
        gates_f, gates_b, w_hh_f, w_hh_b, rnn, hbuf);

    // 3. split conversions for the head
    split_k<<<16384, 256, 0, stream>>>(rnn, rnn_nt16, 8192, 512);
    tsplit_k<<<dim3(8, 4, 32), 256, 0, stream>>>(rnn, rnnT16, 256, 512, 512, 131072, 262144);
    split_k<<<8000, 256, 0, stream>>>(attn_w, attn_ws16, 4000, 512);
    tsplit_k<<<dim3(8, 8, 1), 256, 0, stream>>>(w1, w1t16, 512, 512, 512, 0, 0);
    tsplit_k<<<dim3(4, 8, 1), 256, 0, stream>>>(w2, w2t16, 512, 256, 256, 0, 0);

    // 4. GCN branch on MFMA (runs after lstm in stream order; hbuf region dead)
    split_k<<<4000, 256, 0, stream>>>(label_emb, le16, 4000, 256);
    tsplit_k<<<dim3(8, 4, 1), 256, 0, stream>>>(gcn_w, gw16, 256, 512, 512, 0, 0);
    mgemm_k<false, false, false, true, false><<<dim3(32, 4, 1), 256, 0, stream>>>(
        le16, gw16, gcn_tmp, nullptr,
        4000, 512, 256, 512, 512, 512, 0,
        0L, 0L, 0L, 0L, nullptr, nullptr, 1, 0);
    spmm_k<<<dim3(4000), 256, 0, stream>>>(adj, gcn_tmp, gcn_b, gcn_out);
    split_k<<<8000, 256, 0, stream>>>(gcn_out, go16, 4000, 512);
    tsplit_k<<<dim3(8, 8, 1), 256, 0, stream>>>(w1 + (size_t)512 * 512, w1b16, 512, 512, 512, 0, 0);
    mgemm_k<true, false, false, true, false><<<dim3(32, 4, 1), 256, 0, stream>>>(
        go16, w1b16, contrib, nullptr,
        4000, 512, 512, 1024, 1024, 512, 0,
        0L, 0L, 0L, 0L, b1, nullptr, 1, 0);

    // 5. attention + MLP head (MFMA split-bf16), chunked over batch
    for (int b0 = 0; b0 < 32; b0 += NB) {
        const int nb = (32 - b0 < NB) ? (32 - b0) : NB;
        mgemm_k<false, false, false, true, false><<<dim3(32, 2, nb), 256, 0, stream>>>(
            attn_ws16, rnn_nt16 + (size_t)b0 * 262144, scoresb, nullptr,
            4000, 256, 512, 1024, 1024, 256, 0,
            0L, 262144L, 1024000L, 0L, nullptr, nullptr, 1, 0);
        softmax_split_k<<<dim3(1000, nb), 256, 0, stream>>>(scoresb, tokens, b0);
        mgemm_k<false, false, false, false, true><<<dim3(32, 4, nb), 256, 0, stream>>>(
            (const ushort*)scoresb, rnnT16 + (size_t)b0 * 262144, nullptr, attn16,
            4000, 512, 256, 512, 512, 0, 1024,
            2048000L, 262144L, 0L, 4096000L, nullptr, nullptr, 1, 0);
        mgemm_k<false, true, true, false, true><<<dim3((nb * 4000 + 127) / 128, 4, 1), 256, 0, stream>>>(
            attn16, w1t16, nullptr, x116,
            nb * 4000, 512, 512, 1024, 1024, 0, 1024,
            0L, 0L, 0L, 0L, nullptr, contrib, 4000, 512);
        mgemm_k<true, false, true, true, false><<<dim3((nb * 4000 + 127) / 128, 2, 1), 256, 0, stream>>>(
            x116, w2t16, x2b, nullptr,
            nb * 4000, 256, 512, 1024, 1024, 256, 0,
            0L, 0L, 0L, 0L, b2, nullptr, 1, 0);
        out_k<<<dim3(nb * 1000), 256, 0, stream>>>(x2b, w_out, b_out, outp, b0);
    }
}